// Round 7
// baseline (515.085 us; speedup 1.0000x reference)
//
#include <hip/hip_runtime.h>
#include <math.h>

#define NNODE 2048
#define NEDGE 65536
#define HIDN  256
#define NHEAD 8
#define HDIM  32
#define FFD   1024
#define NLAYER 4
#define OUTD  1280
#define NNZ_MAX (2*NEDGE + NNODE)

typedef __attribute__((ext_vector_type(8))) short bf16x8;
typedef __attribute__((ext_vector_type(4))) float f32x4;

__device__ __forceinline__ unsigned short f2b(float f) {
    unsigned u = __float_as_uint(f);
    unsigned r = (u + 0x7fffu + ((u >> 16) & 1u)) >> 16;
    return (unsigned short)r;
}
__device__ __forceinline__ float b2f(unsigned short u) {
    return __uint_as_float((unsigned)u << 16);
}

// ----------------------------------------------------------- MFMA GEMM -----
// C[M,N] = A[M,K] @ Bt[N,K]^T + bias. 64x64 tile, BK=32, register prefetch.
// EPI: 0=bias, 1=bias+gelu, 3=bias+extra, 4=tanh+pool-reduce(Wp2->sred)
// OUT: 0=fp32 Cf, 1=bf16 Cb, 2=both
template<int K, int EPI, int OUT>
__global__ __launch_bounds__(256)
void mgemm(const unsigned short* __restrict__ A, const unsigned short* __restrict__ Bt,
           const float* __restrict__ bias, const float* __restrict__ extra,
           float* __restrict__ Cf, unsigned short* __restrict__ Cb,
           int M, int N, const float* __restrict__ Wp2, float* __restrict__ sred)
{
    __shared__ __align__(16) unsigned short As[64 * 40];
    __shared__ __align__(16) unsigned short Bs[64 * 40];
    int tid = threadIdx.x;
    int bm0 = blockIdx.y * 64, bn0 = blockIdx.x * 64;
    int wave = tid >> 6, lane = tid & 63;
    int wm = (wave >> 1) * 32, wn = (wave & 1) * 32;
    int srow = tid >> 2, skoff = (tid & 3) * 8;
    int lrow = lane & 15, quad = lane >> 4;
    const unsigned short* ap = A  + (size_t)(bm0 + srow) * K + skoff;
    const unsigned short* bp = Bt + (size_t)(bn0 + srow) * K + skoff;
    uint4 av = *(const uint4*)ap;
    uint4 bv = *(const uint4*)bp;
    f32x4 acc[2][2] = {};
    constexpr int NC = K / 32;
    #pragma unroll 8
    for (int c = 0; c < NC; ++c) {
        *(uint4*)(&As[srow*40 + skoff]) = av;
        *(uint4*)(&Bs[srow*40 + skoff]) = bv;
        __syncthreads();
        if (c + 1 < NC) {
            av = *(const uint4*)(ap + (c+1)*32);
            bv = *(const uint4*)(bp + (c+1)*32);
        }
        bf16x8 af[2], bfr[2];
        #pragma unroll
        for (int i = 0; i < 2; i++) af[i]  = *(const bf16x8*)(&As[(wm + i*16 + lrow)*40 + quad*8]);
        #pragma unroll
        for (int j = 0; j < 2; j++) bfr[j] = *(const bf16x8*)(&Bs[(wn + j*16 + lrow)*40 + quad*8]);
        #pragma unroll
        for (int i = 0; i < 2; i++)
            #pragma unroll
            for (int j = 0; j < 2; j++)
                acc[i][j] = __builtin_amdgcn_mfma_f32_16x16x32_bf16(af[i], bfr[j], acc[i][j], 0, 0, 0);
        __syncthreads();
    }
    if (EPI == 4) {
        #pragma unroll
        for (int i = 0; i < 2; i++) {
            #pragma unroll
            for (int r = 0; r < 4; r++) {
                int row = bm0 + wm + i*16 + quad*4 + r;
                float ps = 0.f;
                #pragma unroll
                for (int j = 0; j < 2; j++) {
                    int col = bn0 + wn + j*16 + lrow;
                    float v = tanhf(acc[i][j][r] + bias[col]);
                    ps += v * Wp2[col];
                }
                ps += __shfl_xor(ps, 1);
                ps += __shfl_xor(ps, 2);
                ps += __shfl_xor(ps, 4);
                ps += __shfl_xor(ps, 8);
                if (lrow == 0) atomicAdd(&sred[row], ps);
            }
        }
        return;
    }
    #pragma unroll
    for (int i = 0; i < 2; i++)
        #pragma unroll
        for (int j = 0; j < 2; j++) {
            int col = bn0 + wn + j*16 + lrow;
            float bvv = bias[col];
            #pragma unroll
            for (int r = 0; r < 4; r++) {
                int row = bm0 + wm + i*16 + quad*4 + r;
                float v = acc[i][j][r] + bvv;
                if (EPI == 1) v = 0.5f * v * (1.f + erff(v * 0.70710678118654752f));
                else if (EPI == 3) v += extra[(size_t)row*N + col];
                if (OUT == 0 || OUT == 2) Cf[(size_t)row*N + col] = v;
                if (OUT == 1 || OUT == 2) Cb[(size_t)row*N + col] = f2b(v);
            }
        }
}

// ------------------------------------------- MFMA GEMM + residual + LN -----
// Tile: 16 rows x 256 cols (full HIDN width) so LayerNorm fuses in-epilogue.
// X = LN(res + A@Bt^T + bias) [ * second LN if DOUBLE ]; writes fp32 X + bf16 Xb.
template<int K, bool DOUBLE>
__global__ __launch_bounds__(256)
void mgemm_ln(const unsigned short* __restrict__ A, const unsigned short* __restrict__ Bt,
              const float* __restrict__ bias, const float* __restrict__ res,
              const float* __restrict__ ga, const float* __restrict__ ba,
              const float* __restrict__ gb, const float* __restrict__ bb,
              float* __restrict__ X, unsigned short* __restrict__ Xb)
{
    __shared__ __align__(16) unsigned short As[16 * 40];
    __shared__ __align__(16) unsigned short Bs[256 * 40];
    __shared__ float rsum[4][16], rsq[4][16], rsum2[4][16], rsq2[4][16];
    int tid = threadIdx.x;
    int bm0 = blockIdx.x * 16;
    int w = tid >> 6, lane = tid & 63;
    int lrow = lane & 15, quad = lane >> 4;
    int arow = tid >> 2, akoff = (tid & 3) * 8;    // tid<64 stages A
    const unsigned short* ap = A + (size_t)(bm0 + arow) * K + akoff;
    const unsigned short* bp = Bt + (size_t)tid * K;  // thread stages B row tid
    uint4 av, bv0, bv1, bv2, bv3;
    if (tid < 64) av = *(const uint4*)ap;
    bv0 = *(const uint4*)(bp + 0);
    bv1 = *(const uint4*)(bp + 8);
    bv2 = *(const uint4*)(bp + 16);
    bv3 = *(const uint4*)(bp + 24);
    f32x4 acc[4] = {};
    constexpr int NC = K / 32;
    #pragma unroll 8
    for (int c = 0; c < NC; ++c) {
        if (tid < 64) *(uint4*)(&As[arow*40 + akoff]) = av;
        *(uint4*)(&Bs[tid*40 + 0])  = bv0;
        *(uint4*)(&Bs[tid*40 + 8])  = bv1;
        *(uint4*)(&Bs[tid*40 + 16]) = bv2;
        *(uint4*)(&Bs[tid*40 + 24]) = bv3;
        __syncthreads();
        if (c + 1 < NC) {
            if (tid < 64) av = *(const uint4*)(ap + (c+1)*32);
            bv0 = *(const uint4*)(bp + (c+1)*32 + 0);
            bv1 = *(const uint4*)(bp + (c+1)*32 + 8);
            bv2 = *(const uint4*)(bp + (c+1)*32 + 16);
            bv3 = *(const uint4*)(bp + (c+1)*32 + 24);
        }
        bf16x8 af = *(const bf16x8*)(&As[lrow*40 + quad*8]);
        #pragma unroll
        for (int j = 0; j < 4; j++) {
            bf16x8 bf = *(const bf16x8*)(&Bs[(w*64 + j*16 + lrow)*40 + quad*8]);
            acc[j] = __builtin_amdgcn_mfma_f32_16x16x32_bf16(af, bf, acc[j], 0, 0, 0);
        }
        __syncthreads();
    }
    // epilogue: v = acc + bias + res; two-pass LN over 256 cols
    float v[4][4];
    #pragma unroll
    for (int j = 0; j < 4; j++) {
        int col = w*64 + j*16 + lrow;
        float bvv = bias[col];
        #pragma unroll
        for (int r = 0; r < 4; r++) {
            int row = bm0 + quad*4 + r;
            v[j][r] = acc[j][r] + bvv + res[(size_t)row*HIDN + col];
        }
    }
    float mean[4], rsv[4];
    #pragma unroll
    for (int r = 0; r < 4; r++) {
        float s = v[0][r] + v[1][r] + v[2][r] + v[3][r];
        s += __shfl_xor(s, 1); s += __shfl_xor(s, 2);
        s += __shfl_xor(s, 4); s += __shfl_xor(s, 8);
        if (lrow == 0) rsum[w][quad*4 + r] = s;
    }
    __syncthreads();
    #pragma unroll
    for (int r = 0; r < 4; r++) {
        int rr = quad*4 + r;
        mean[r] = (rsum[0][rr] + rsum[1][rr] + rsum[2][rr] + rsum[3][rr]) * (1.f/HIDN);
        float q = 0.f;
        #pragma unroll
        for (int j = 0; j < 4; j++) { float d = v[j][r] - mean[r]; q += d*d; }
        q += __shfl_xor(q, 1); q += __shfl_xor(q, 2);
        q += __shfl_xor(q, 4); q += __shfl_xor(q, 8);
        if (lrow == 0) rsq[w][rr] = q;
    }
    __syncthreads();
    #pragma unroll
    for (int r = 0; r < 4; r++) {
        int rr = quad*4 + r;
        float var = (rsq[0][rr] + rsq[1][rr] + rsq[2][rr] + rsq[3][rr]) * (1.f/HIDN);
        rsv[r] = rsqrtf(var + 1e-5f);
    }
    #pragma unroll
    for (int j = 0; j < 4; j++) {
        int col = w*64 + j*16 + lrow;
        float gv = ga[col], bvv = ba[col];
        #pragma unroll
        for (int r = 0; r < 4; r++)
            v[j][r] = (v[j][r] - mean[r]) * rsv[r] * gv + bvv;
    }
    if (DOUBLE) {
        #pragma unroll
        for (int r = 0; r < 4; r++) {
            float s = v[0][r] + v[1][r] + v[2][r] + v[3][r];
            s += __shfl_xor(s, 1); s += __shfl_xor(s, 2);
            s += __shfl_xor(s, 4); s += __shfl_xor(s, 8);
            if (lrow == 0) rsum2[w][quad*4 + r] = s;
        }
        __syncthreads();
        #pragma unroll
        for (int r = 0; r < 4; r++) {
            int rr = quad*4 + r;
            mean[r] = (rsum2[0][rr] + rsum2[1][rr] + rsum2[2][rr] + rsum2[3][rr]) * (1.f/HIDN);
            float q = 0.f;
            #pragma unroll
            for (int j = 0; j < 4; j++) { float d = v[j][r] - mean[r]; q += d*d; }
            q += __shfl_xor(q, 1); q += __shfl_xor(q, 2);
            q += __shfl_xor(q, 4); q += __shfl_xor(q, 8);
            if (lrow == 0) rsq2[w][rr] = q;
        }
        __syncthreads();
        #pragma unroll
        for (int r = 0; r < 4; r++) {
            int rr = quad*4 + r;
            float var = (rsq2[0][rr] + rsq2[1][rr] + rsq2[2][rr] + rsq2[3][rr]) * (1.f/HIDN);
            rsv[r] = rsqrtf(var + 1e-5f);
        }
        #pragma unroll
        for (int j = 0; j < 4; j++) {
            int col = w*64 + j*16 + lrow;
            float gv = gb[col], bvv = bb[col];
            #pragma unroll
            for (int r = 0; r < 4; r++)
                v[j][r] = (v[j][r] - mean[r]) * rsv[r] * gv + bvv;
        }
    }
    #pragma unroll
    for (int j = 0; j < 4; j++) {
        int col = w*64 + j*16 + lrow;
        #pragma unroll
        for (int r = 0; r < 4; r++) {
            int row = bm0 + quad*4 + r;
            X[(size_t)row*HIDN + col] = v[j][r];
            Xb[(size_t)row*HIDN + col] = f2b(v[j][r]);
        }
    }
}

// ------------------------------------------------- weight prep (per call) --
// All weight transposes + nf convert + bias concat in ONE launch.
__global__ __launch_bounds__(256)
void transpose_all(const float* __restrict__ Wq, const float* __restrict__ Wk,
                   const float* __restrict__ Wv, const float* __restrict__ Wo,
                   const float* __restrict__ Wf1, const float* __restrict__ Wf2,
                   const float* __restrict__ W_node, const float* __restrict__ Wp1,
                   unsigned short* __restrict__ WqkvT, unsigned short* __restrict__ WoT,
                   unsigned short* __restrict__ Wf1T, unsigned short* __restrict__ Wf2T,
                   unsigned short* __restrict__ WnT, unsigned short* __restrict__ Wp1T,
                   const float* __restrict__ nf, unsigned short* __restrict__ nf_b,
                   const float* __restrict__ bq, const float* __restrict__ bk,
                   const float* __restrict__ bv, float* __restrict__ bqkv)
{
    __shared__ unsigned short tile[32][33];
    int bid = blockIdx.x;
    if (bid >= 3168) {   // misc region: nf bf16 convert + qkv bias concat
        int t = (bid - 3168) * 256 + threadIdx.x;
        if (t < NNODE*128) {
            nf_b[t] = f2b(nf[t]);
        } else {
            int u = t - NNODE*128;
            if (u < NLAYER*768) {
                int l = u / 768, j = u % 768;
                float vv = (j < 256) ? bq[l*256 + j] : (j < 512 ? bk[l*256 + j - 256] : bv[l*256 + j - 512]);
                bqkv[u] = vv;
            }
        }
        return;
    }
    const float* s; unsigned short* d; int K, N, n0, k0;
    if (bid < 1024) {
        int mat = bid >> 6, rem = bid & 63;
        int m4 = mat & 3, l = mat >> 2;
        s = (m4 == 0 ? Wq : m4 == 1 ? Wk : m4 == 2 ? Wv : Wo) + (size_t)l * 65536;
        d = (m4 < 3) ? WqkvT + (size_t)l*196608 + (size_t)m4*65536
                     : WoT + (size_t)l*65536;
        K = 256; N = 256; n0 = (rem & 7) * 32; k0 = (rem >> 3) * 32;
    } else if (bid < 2048) {
        int idx = bid - 1024; int l = idx >> 8, rem = idx & 255;
        s = Wf1 + (size_t)l*262144; d = Wf1T + (size_t)l*262144;
        K = 256; N = 1024; n0 = (rem & 31) * 32; k0 = (rem >> 5) * 32;
    } else if (bid < 3072) {
        int idx = bid - 2048; int l = idx >> 8, rem = idx & 255;
        s = Wf2 + (size_t)l*262144; d = Wf2T + (size_t)l*262144;
        K = 1024; N = 256; n0 = (rem & 7) * 32; k0 = (rem >> 3) * 32;
    } else if (bid < 3104) {
        int rem = bid - 3072;
        s = W_node; d = WnT;
        K = 128; N = 256; n0 = (rem & 7) * 32; k0 = (rem >> 3) * 32;
    } else {
        int rem = bid - 3104;
        s = Wp1; d = Wp1T;
        K = 256; N = 256; n0 = (rem & 7) * 32; k0 = (rem >> 3) * 32;
    }
    int tx = threadIdx.x & 31, ty = threadIdx.x >> 5;
    #pragma unroll
    for (int i = 0; i < 4; i++)
        tile[ty + i*8][tx] = f2b(s[(size_t)(k0 + ty + i*8) * N + n0 + tx]);
    __syncthreads();
    #pragma unroll
    for (int i = 0; i < 4; i++)
        d[(size_t)(n0 + ty + i*8) * K + k0 + tx] = tile[tx][ty + i*8];
}

// ------------------------------------------------------- adjacency / CSR ---
__global__ void adj_build(const int* __restrict__ src, const int* __restrict__ dst,
                          unsigned* __restrict__ adjbits)
{
    int t = blockIdx.x * blockDim.x + threadIdx.x;
    if (t < NEDGE) {
        int s = src[t], d = dst[t];
        atomicOr(&adjbits[(size_t)s*64 + (d >> 5)], 1u << (d & 31));
        atomicOr(&adjbits[(size_t)d*64 + (s >> 5)], 1u << (s & 31));
    }
    if (t < NNODE)
        atomicOr(&adjbits[(size_t)t*64 + (t >> 5)], 1u << (t & 31));
}

__global__ void row_rank(const unsigned* __restrict__ adjbits,
                         unsigned* __restrict__ rowcum, int* __restrict__ deg)
{
    int i = blockIdx.x * blockDim.x + threadIdx.x;
    if (i >= NNODE) return;
    unsigned c = 0;
    for (int w = 0; w < 64; w++) {
        rowcum[i*64 + w] = c;
        c += __popc(adjbits[i*64 + w]);
    }
    deg[i] = (int)c;
}

__global__ __launch_bounds__(256)
void scan_kernel(const int* __restrict__ deg, int* __restrict__ rowoff)
{
    __shared__ int part[256];
    int tid = threadIdx.x;
    int base = tid * 8;
    int local[8]; int s = 0;
    #pragma unroll
    for (int k = 0; k < 8; k++) { local[k] = s; s += deg[base + k]; }
    part[tid] = s;
    __syncthreads();
    for (int off = 1; off < 256; off <<= 1) {
        int v = (tid >= off) ? part[tid - off] : 0;
        __syncthreads();
        part[tid] += v;
        __syncthreads();
    }
    int pre = (tid == 0) ? 0 : part[tid - 1];
    #pragma unroll
    for (int k = 0; k < 8; k++) rowoff[base + k] = pre + local[k];
    if (tid == 255) rowoff[NNODE] = part[255];
}

__global__ __launch_bounds__(256)
void fill_cols(const unsigned* __restrict__ adjbits, const int* __restrict__ rowoff,
               const unsigned* __restrict__ rowcum, int* __restrict__ cols)
{
    int t = blockIdx.x * 256 + threadIdx.x;
    int i = t >> 6, w = t & 63;
    unsigned bits = adjbits[(size_t)i*64 + w];
    int base = rowoff[i] + (int)rowcum[(size_t)i*64 + w];
    while (bits) {
        int b = __ffs(bits) - 1;
        cols[base++] = w*32 + b;
        bits &= bits - 1;
    }
}

__global__ void wcomb_kernel(const float* __restrict__ W_edge, const float* __restrict__ b_edge,
                             const float* __restrict__ Wep, const float* __restrict__ bep,
                             float* __restrict__ Wcomb, float* __restrict__ bcomb)
{
    int t = blockIdx.x * blockDim.x + threadIdx.x;
    if (t < 64*32) {
        int k = t >> 5, lh = t & 31, l = lh >> 3, h = lh & 7;
        float acc = 0.f;
        for (int c = 0; c < HIDN; c++)
            acc += W_edge[k*HIDN + c] * Wep[l*HIDN*NHEAD + c*NHEAD + h];
        Wcomb[k*32 + lh] = acc;
    } else if (t < 64*32 + 32) {
        int lh = t - 64*32, l = lh >> 3, h = lh & 7;
        float acc = bep[l*NHEAD + h];
        for (int c = 0; c < HIDN; c++)
            acc += b_edge[c] * Wep[l*HIDN*NHEAD + c*NHEAD + h];
        bcomb[lh] = acc;
    }
}

__global__ __launch_bounds__(256)
void edge_bias_scatter(const float* __restrict__ ef, const float* __restrict__ Wcomb,
                       const float* __restrict__ bcomb,
                       const int* __restrict__ src, const int* __restrict__ dst,
                       const unsigned* __restrict__ adjbits,
                       const unsigned* __restrict__ rowcum,
                       const int* __restrict__ rowoff, float* __restrict__ bias_csr)
{
    __shared__ float Wl[64*32];
    __shared__ float bl[32];
    int tid = threadIdx.x;
    for (int k = tid; k < 64*32; k += 256) Wl[k] = Wcomb[k];
    if (tid < 32) bl[tid] = bcomb[tid];
    __syncthreads();
    int t = blockIdx.x * 256 + tid;
    int e = t >> 5, lh = t & 31;
    const float* f = ef + (size_t)e * 64;
    float acc = bl[lh];
    #pragma unroll
    for (int k = 0; k < 64; k++) acc += f[k] * Wl[k*32 + lh];
    int s = src[e], d = dst[e];
    unsigned wbits = adjbits[(size_t)s*64 + (d >> 5)];
    int rank = (int)rowcum[(size_t)s*64 + (d >> 5)] + __popc(wbits & ((1u << (d & 31)) - 1u));
    int slot = rowoff[s] + rank;
    atomicAdd(&bias_csr[(size_t)slot*32 + lh], acc);
}

// ------------------------------------------------------- sparse attention --
__global__ __launch_bounds__(256)
void attn_kernel(const unsigned short* __restrict__ QKVb, const int* __restrict__ rowoff,
                 const int* __restrict__ cols, const float* __restrict__ bias_csr,
                 unsigned short* __restrict__ ctxb, int layer)
{
    __shared__ float mS[4][8], lS[4][8];
    __shared__ __align__(16) float accS[4][256];
    int i = blockIdx.x;
    int tid = threadIdx.x;
    int w = tid >> 6, lane = tid & 63;
    int h = lane >> 3;
    int off = lane * 4;
    ushort4 qu = *(const ushort4*)(QKVb + (size_t)i*768 + off);
    float4 qf = { b2f(qu.x), b2f(qu.y), b2f(qu.z), b2f(qu.w) };
    int start = rowoff[i], end = rowoff[i+1];
    int lh0 = layer * 8 + h;
    float m = -INFINITY, l = 0.f;
    float4 acc = {0.f, 0.f, 0.f, 0.f};
    for (int c0 = start + w; c0 < end; c0 += 256) {
        int myslot = c0 + 4*lane;
        int mycol = (myslot < end) ? cols[myslot] : 0;
        int lim = min(end, c0 + 256);
        int it = 0;
        for (int slot = c0; slot < lim; slot += 4, ++it) {
            int j = __shfl(mycol, it);
            ushort4 ku = *(const ushort4*)(QKVb + (size_t)j*768 + 256 + off);
            float s = qf.x*b2f(ku.x) + qf.y*b2f(ku.y) + qf.z*b2f(ku.z) + qf.w*b2f(ku.w);
            s += __shfl_xor(s, 1);
            s += __shfl_xor(s, 2);
            s += __shfl_xor(s, 4);
            s = s * 0.17677669529663687f + bias_csr[(size_t)slot*32 + lh0];
            float mn = fmaxf(m, s);
            float sc = __expf(m - mn);
            float p  = __expf(s - mn);
            ushort4 vu = *(const ushort4*)(QKVb + (size_t)j*768 + 512 + off);
            acc.x = acc.x*sc + p*b2f(vu.x);
            acc.y = acc.y*sc + p*b2f(vu.y);
            acc.z = acc.z*sc + p*b2f(vu.z);
            acc.w = acc.w*sc + p*b2f(vu.w);
            l = l*sc + p;
            m = mn;
        }
    }
    if ((lane & 7) == 0) { mS[w][h] = m; lS[w][h] = l; }
    *(float4*)&accS[w][off] = acc;
    __syncthreads();
    if (w == 0) {
        float m0 = mS[0][h], m1 = mS[1][h], m2 = mS[2][h], m3 = mS[3][h];
        float mx = fmaxf(fmaxf(m0, m1), fmaxf(m2, m3));
        float e0 = (m0 == -INFINITY) ? 0.f : __expf(m0 - mx);
        float e1 = (m1 == -INFINITY) ? 0.f : __expf(m1 - mx);
        float e2 = (m2 == -INFINITY) ? 0.f : __expf(m2 - mx);
        float e3 = (m3 == -INFINITY) ? 0.f : __expf(m3 - mx);
        float ls = lS[0][h]*e0 + lS[1][h]*e1 + lS[2][h]*e2 + lS[3][h]*e3;
        float4 a0 = *(float4*)&accS[0][off];
        float4 a1 = *(float4*)&accS[1][off];
        float4 a2 = *(float4*)&accS[2][off];
        float4 a3 = *(float4*)&accS[3][off];
        float inv = 1.f / ls;
        ushort4 o;
        o.x = f2b((a0.x*e0 + a1.x*e1 + a2.x*e2 + a3.x*e3) * inv);
        o.y = f2b((a0.y*e0 + a1.y*e1 + a2.y*e2 + a3.y*e3) * inv);
        o.z = f2b((a0.z*e0 + a1.z*e1 + a2.z*e2 + a3.z*e3) * inv);
        o.w = f2b((a0.w*e0 + a1.w*e1 + a2.w*e2 + a3.w*e3) * inv);
        *(ushort4*)(ctxb + (size_t)i*HIDN + off) = o;
    }
}

// ----------------------------------------- pooling: 16-block partials ------
__global__ __launch_bounds__(256)
void pool_part(const float* __restrict__ x, const float* __restrict__ sred,
               float* __restrict__ partial)
{
    __shared__ float red[4];
    __shared__ float aw[128];
    int b = blockIdx.x, tid = threadIdx.x;
    float mxs = -INFINITY;
    for (int r = tid; r < NNODE; r += 256) mxs = fmaxf(mxs, sred[r]);
    for (int mm = 1; mm < 64; mm <<= 1) mxs = fmaxf(mxs, __shfl_xor(mxs, mm));
    if ((tid & 63) == 0) red[tid >> 6] = mxs;
    __syncthreads();
    mxs = fmaxf(fmaxf(red[0], red[1]), fmaxf(red[2], red[3]));
    __syncthreads();
    float ss = 0.f;
    for (int r = tid; r < NNODE; r += 256) ss += __expf(sred[r] - mxs);
    for (int mm = 1; mm < 64; mm <<= 1) ss += __shfl_xor(ss, mm);
    if ((tid & 63) == 0) red[tid >> 6] = ss;
    __syncthreads();
    ss = red[0] + red[1] + red[2] + red[3];
    float inv = 1.f / ss;
    int r0 = b * 128;
    if (tid < 128) aw[tid] = __expf(sred[r0 + tid] - mxs) * inv;
    __syncthreads();
    float sm = 0.f, mx = -INFINITY, ap = 0.f;
    for (int r = 0; r < 128; r++) {
        float v = x[(size_t)(r0 + r)*HIDN + tid];
        sm += v;
        mx = fmaxf(mx, v);
        ap += v * aw[r];
    }
    partial[(size_t)b*768 + tid]       = sm;
    partial[(size_t)b*768 + 256 + tid] = mx;
    partial[(size_t)b*768 + 512 + tid] = ap;
}

__global__ __launch_bounds__(256)
void pool_fin(const float* __restrict__ partial, float* __restrict__ g)
{
    int c = threadIdx.x;
    float sm = 0.f, mx = -INFINITY, ap = 0.f;
    for (int b = 0; b < 16; b++) {
        sm += partial[(size_t)b*768 + c];
        mx = fmaxf(mx, partial[(size_t)b*768 + 256 + c]);
        ap += partial[(size_t)b*768 + 512 + c];
    }
    g[c]          = sm * (1.f / NNODE);
    g[HIDN + c]   = mx;
    g[2*HIDN + c] = ap;
}

// --------------------------------------------------------------- head ------
__global__ __launch_bounds__(256)
void head1(const float* __restrict__ g, const float* __restrict__ Wo1,
           const float* __restrict__ bo1, float* __restrict__ h1)
{
    __shared__ float hp[4][64];
    int tid = threadIdx.x;
    int w = tid >> 6, lane = tid & 63;
    int j = blockIdx.x * 64 + lane;
    float acc = 0.f;
    int k0 = w * 192;
    for (int k = k0; k < k0 + 192; k++)
        acc += g[k] * Wo1[(size_t)k*512 + j];
    hp[w][lane] = acc;
    __syncthreads();
    if (w == 0) {
        float s = hp[0][lane] + hp[1][lane] + hp[2][lane] + hp[3][lane] + bo1[j];
        h1[j] = fmaxf(s, 0.f);
    }
}

__global__ __launch_bounds__(256)
void head2(const float* __restrict__ h1, const float* __restrict__ Wo2,
           const float* __restrict__ bo2, float* __restrict__ out)
{
    __shared__ float hp[4][64];
    int tid = threadIdx.x;
    int w = tid >> 6, lane = tid & 63;
    int j = blockIdx.x * 64 + lane;
    float acc = 0.f;
    int k0 = w * 128;
    for (int k = k0; k < k0 + 128; k++)
        acc += h1[k] * Wo2[(size_t)k*OUTD + j];
    hp[w][lane] = acc;
    __syncthreads();
    if (w == 0)
        out[j] = hp[0][lane] + hp[1][lane] + hp[2][lane] + hp[3][lane] + bo2[j];
}

// ------------------------------------------------------------- launch ------
extern "C" void kernel_launch(void* const* d_in, const int* in_sizes, int n_in,
                              void* d_out, int out_size, void* d_ws, size_t ws_size,
                              hipStream_t stream)
{
    const float* node_features = (const float*)d_in[0];
    const float* edge_features = (const float*)d_in[1];
    const int*   edge_index    = (const int*)d_in[2];
    const float* W_node = (const float*)d_in[3];
    const float* b_node = (const float*)d_in[4];
    const float* W_edge = (const float*)d_in[5];
    const float* b_edge = (const float*)d_in[6];
    const float* pos_emb = (const float*)d_in[7];
    const float* Wq = (const float*)d_in[8];
    const float* bq = (const float*)d_in[9];
    const float* Wk = (const float*)d_in[10];
    const float* bk = (const float*)d_in[11];
    const float* Wv = (const float*)d_in[12];
    const float* bv = (const float*)d_in[13];
    const float* Wo = (const float*)d_in[14];
    const float* bo = (const float*)d_in[15];
    const float* Wep = (const float*)d_in[16];
    const float* bep = (const float*)d_in[17];
    const float* Wf1 = (const float*)d_in[18];
    const float* bf1 = (const float*)d_in[19];
    const float* Wf2 = (const float*)d_in[20];
    const float* bf2 = (const float*)d_in[21];
    const float* g1  = (const float*)d_in[22];
    const float* be1 = (const float*)d_in[23];
    const float* g2  = (const float*)d_in[24];
    const float* be2 = (const float*)d_in[25];
    const float* g_ln = (const float*)d_in[26];
    const float* b_ln = (const float*)d_in[27];
    const float* Wp1 = (const float*)d_in[28];
    const float* bp1 = (const float*)d_in[29];
    const float* Wp2 = (const float*)d_in[30];
    const float* bp2 = (const float*)d_in[31];
    const float* Wo1 = (const float*)d_in[32];
    const float* bo1 = (const float*)d_in[33];
    const float* Wo2 = (const float*)d_in[34];
    const float* bo2 = (const float*)d_in[35];
    (void)bp2;
    const int* src = edge_index;
    const int* dst = edge_index + NEDGE;

    char* w = (char*)d_ws;
    auto carve = [&](size_t nbytes) {
        void* p = (void*)w;
        w += (nbytes + 255) & ~(size_t)255;
        return p;
    };
    float* x        = (float*)carve((size_t)NNODE*HIDN*4);
    unsigned short* xb = (unsigned short*)carve((size_t)NNODE*HIDN*2);
    unsigned short* bufQKVb = (unsigned short*)carve((size_t)NNODE*768*2);
    unsigned short* bufAb = (unsigned short*)carve((size_t)NNODE*HIDN*2);
    unsigned short* bufFb = (unsigned short*)carve((size_t)NNODE*FFD*2);
    float* Wcomb    = (float*)carve(64*32*4);
    float* bcomb    = (float*)carve(32*4);
    // adjbits + bias_csr + sbuf contiguous -> single memset
    unsigned* adjbits = (unsigned*)carve((size_t)NNODE*64*4);
    float* bias_csr = (float*)carve((size_t)NNZ_MAX*32*4);
    float* sbuf  = (float*)carve(NNODE*4);
    unsigned* rowcum  = (unsigned*)carve((size_t)NNODE*64*4);
    int* deg    = (int*)carve(NNODE*4);
    int* rowoff = (int*)carve((NNODE+1)*4);
    int* colsb  = (int*)carve((size_t)NNZ_MAX*4);
    float* gbuf  = (float*)carve(3*HIDN*4);
    float* partial = (float*)carve(16*768*4);
    float* h1buf = (float*)carve(512*4);
    unsigned short* nf_b  = (unsigned short*)carve((size_t)NNODE*128*2);
    unsigned short* WnT   = (unsigned short*)carve((size_t)HIDN*128*2);
    unsigned short* WqkvT = (unsigned short*)carve((size_t)NLAYER*768*HIDN*2);
    float*          bqkv  = (float*)carve((size_t)NLAYER*768*4);
    unsigned short* WoT   = (unsigned short*)carve((size_t)NLAYER*HIDN*HIDN*2);
    unsigned short* Wf1T  = (unsigned short*)carve((size_t)NLAYER*FFD*HIDN*2);
    unsigned short* Wf2T  = (unsigned short*)carve((size_t)NLAYER*HIDN*FFD*2);
    unsigned short* Wp1T  = (unsigned short*)carve((size_t)HIDN*HIDN*2);

    // ---- zero adjbits + bias_csr + sbuf in one shot ----
    hipMemsetAsync(adjbits, 0,
                   (size_t)NNODE*64*4 + (size_t)NNZ_MAX*32*4 + (size_t)NNODE*4, stream);
    adj_build<<<(NEDGE+255)/256, 256, 0, stream>>>(src, dst, adjbits);
    row_rank<<<NNODE/256, 256, 0, stream>>>(adjbits, rowcum, deg);
    scan_kernel<<<1, 256, 0, stream>>>(deg, rowoff);
    fill_cols<<<(NNODE*64)/256, 256, 0, stream>>>(adjbits, rowoff, rowcum, colsb);
    wcomb_kernel<<<(64*32+32+255)/256, 256, 0, stream>>>(W_edge, b_edge, Wep, bep, Wcomb, bcomb);
    edge_bias_scatter<<<(NEDGE*32)/256, 256, 0, stream>>>(
        edge_features, Wcomb, bcomb, src, dst, adjbits, rowcum, rowoff, bias_csr);

    // ---- weight prep (transposes + nf convert + bias concat, one launch) ----
    transpose_all<<<3168 + 1024 + 12, 256, 0, stream>>>(
        Wq, Wk, Wv, Wo, Wf1, Wf2, W_node, Wp1,
        WqkvT, WoT, Wf1T, Wf2T, WnT, Wp1T,
        node_features, nf_b, bq, bk, bv, bqkv);

    // ---- node encoding ----
    mgemm<128,3,2><<<dim3(HIDN/64, NNODE/64), 256, 0, stream>>>(
        nf_b, WnT, b_node, pos_emb, x, xb, NNODE, HIDN, nullptr, nullptr);

    // ---- transformer layers (5 dispatches each) ----
    for (int l = 0; l < NLAYER; l++) {
        mgemm<256,0,1><<<dim3(768/64, NNODE/64), 256, 0, stream>>>(
            xb, WqkvT + (size_t)l*768*HIDN, bqkv + l*768, nullptr, nullptr, bufQKVb, NNODE, 768, nullptr, nullptr);
        attn_kernel<<<NNODE, 256, 0, stream>>>(bufQKVb, rowoff, colsb, bias_csr, bufAb, l);
        mgemm_ln<256,false><<<NNODE/16, 256, 0, stream>>>(
            bufAb, WoT + (size_t)l*HIDN*HIDN, bo + l*HIDN, x,
            g1 + l*HIDN, be1 + l*HIDN, nullptr, nullptr, x, xb);
        mgemm<256,1,1><<<dim3(FFD/64, NNODE/64), 256, 0, stream>>>(
            xb, Wf1T + (size_t)l*FFD*HIDN, bf1 + l*FFD, nullptr, nullptr, bufFb, NNODE, FFD, nullptr, nullptr);
        if (l < NLAYER - 1)
            mgemm_ln<1024,false><<<NNODE/16, 256, 0, stream>>>(
                bufFb, Wf2T + (size_t)l*HIDN*FFD, bf2 + l*HIDN, x,
                g2 + l*HIDN, be2 + l*HIDN, nullptr, nullptr, x, xb);
        else
            mgemm_ln<1024,true><<<NNODE/16, 256, 0, stream>>>(
                bufFb, Wf2T + (size_t)l*HIDN*FFD, bf2 + l*HIDN, x,
                g2 + l*HIDN, be2 + l*HIDN, g_ln, b_ln, x, xb);
    }

    // ---- pooling (Wp1 GEMM fused with score reduce) + head ----
    mgemm<256,4,0><<<dim3(HIDN/64, NNODE/64), 256, 0, stream>>>(
        xb, Wp1T, bp1, nullptr, nullptr, nullptr, NNODE, HIDN, Wp2, sbuf);
    pool_part<<<16, 256, 0, stream>>>(x, sbuf, partial);
    pool_fin<<<1, 256, 0, stream>>>(partial, gbuf);
    head1<<<8, 256, 0, stream>>>(gbuf, Wo1, bo1, h1buf);
    head2<<<OUTD/64, 256, 0, stream>>>(h1buf, Wo2, bo2, (float*)d_out);
}

// Round 8
// 483.718 us; speedup vs baseline: 1.0648x; 1.0648x over previous
//
#include <hip/hip_runtime.h>
#include <math.h>

#define NNODE 2048
#define NEDGE 65536
#define HIDN  256
#define NHEAD 8
#define HDIM  32
#define FFD   1024
#define NLAYER 4
#define OUTD  1280
#define NNZ_MAX (2*NEDGE + NNODE)

typedef __attribute__((ext_vector_type(8))) short bf16x8;
typedef __attribute__((ext_vector_type(4))) float f32x4;

__device__ __forceinline__ unsigned short f2b(float f) {
    unsigned u = __float_as_uint(f);
    unsigned r = (u + 0x7fffu + ((u >> 16) & 1u)) >> 16;
    return (unsigned short)r;
}
__device__ __forceinline__ float b2f(unsigned short u) {
    return __uint_as_float((unsigned)u << 16);
}

// ----------------------------------------------------------- MFMA GEMM -----
// C[M,N] = A[M,K] @ Bt[N,K]^T + bias. 64x64 tile, BK=32, register prefetch.
// EPI: 0=bias, 1=bias+gelu, 3=bias+extra, 4=tanh+pool-reduce(Wp2->sred)
// OUT: 0=fp32 Cf, 1=bf16 Cb, 2=both
template<int K, int EPI, int OUT>
__global__ __launch_bounds__(256)
void mgemm(const unsigned short* __restrict__ A, const unsigned short* __restrict__ Bt,
           const float* __restrict__ bias, const float* __restrict__ extra,
           float* __restrict__ Cf, unsigned short* __restrict__ Cb,
           int M, int N, const float* __restrict__ Wp2, float* __restrict__ sred)
{
    __shared__ __align__(16) unsigned short As[64 * 40];
    __shared__ __align__(16) unsigned short Bs[64 * 40];
    int tid = threadIdx.x;
    int bm0 = blockIdx.y * 64, bn0 = blockIdx.x * 64;
    int wave = tid >> 6, lane = tid & 63;
    int wm = (wave >> 1) * 32, wn = (wave & 1) * 32;
    int srow = tid >> 2, skoff = (tid & 3) * 8;
    int lrow = lane & 15, quad = lane >> 4;
    const unsigned short* ap = A  + (size_t)(bm0 + srow) * K + skoff;
    const unsigned short* bp = Bt + (size_t)(bn0 + srow) * K + skoff;
    uint4 av = *(const uint4*)ap;
    uint4 bv = *(const uint4*)bp;
    f32x4 acc[2][2] = {};
    constexpr int NC = K / 32;
    #pragma unroll 8
    for (int c = 0; c < NC; ++c) {
        *(uint4*)(&As[srow*40 + skoff]) = av;
        *(uint4*)(&Bs[srow*40 + skoff]) = bv;
        __syncthreads();
        if (c + 1 < NC) {
            av = *(const uint4*)(ap + (c+1)*32);
            bv = *(const uint4*)(bp + (c+1)*32);
        }
        bf16x8 af[2], bfr[2];
        #pragma unroll
        for (int i = 0; i < 2; i++) af[i]  = *(const bf16x8*)(&As[(wm + i*16 + lrow)*40 + quad*8]);
        #pragma unroll
        for (int j = 0; j < 2; j++) bfr[j] = *(const bf16x8*)(&Bs[(wn + j*16 + lrow)*40 + quad*8]);
        #pragma unroll
        for (int i = 0; i < 2; i++)
            #pragma unroll
            for (int j = 0; j < 2; j++)
                acc[i][j] = __builtin_amdgcn_mfma_f32_16x16x32_bf16(af[i], bfr[j], acc[i][j], 0, 0, 0);
        __syncthreads();
    }
    if (EPI == 4) {
        #pragma unroll
        for (int i = 0; i < 2; i++) {
            #pragma unroll
            for (int r = 0; r < 4; r++) {
                int row = bm0 + wm + i*16 + quad*4 + r;
                float ps = 0.f;
                #pragma unroll
                for (int j = 0; j < 2; j++) {
                    int col = bn0 + wn + j*16 + lrow;
                    float v = tanhf(acc[i][j][r] + bias[col]);
                    ps += v * Wp2[col];
                }
                ps += __shfl_xor(ps, 1);
                ps += __shfl_xor(ps, 2);
                ps += __shfl_xor(ps, 4);
                ps += __shfl_xor(ps, 8);
                if (lrow == 0) atomicAdd(&sred[row], ps);
            }
        }
        return;
    }
    #pragma unroll
    for (int i = 0; i < 2; i++)
        #pragma unroll
        for (int j = 0; j < 2; j++) {
            int col = bn0 + wn + j*16 + lrow;
            float bvv = bias[col];
            #pragma unroll
            for (int r = 0; r < 4; r++) {
                int row = bm0 + wm + i*16 + quad*4 + r;
                float v = acc[i][j][r] + bvv;
                if (EPI == 1) v = 0.5f * v * (1.f + erff(v * 0.70710678118654752f));
                else if (EPI == 3) v += extra[(size_t)row*N + col];
                if (OUT == 0 || OUT == 2) Cf[(size_t)row*N + col] = v;
                if (OUT == 1 || OUT == 2) Cb[(size_t)row*N + col] = f2b(v);
            }
        }
}

// --------------------------------- MFMA GEMM with LN-prologue (K=256) ------
// A-tile = LN(pre + res) computed in-registers (4 threads/row, 64 cols each),
// optionally double-LN (DBL). bn==0 block column persists LN state to xout.
// B staging identical to mgemm (coalesced, register prefetch). 64x64 tile.
// EPI: 0=bias, 1=bias+gelu, 4=tanh+pool-reduce. OUT: 0=fp32, 1=bf16.
template<int EPI, int OUT, bool DBL>
__global__ __launch_bounds__(256)
void mgemm_pro(const float* __restrict__ pre, const float* __restrict__ res,
               const unsigned short* __restrict__ Bt, const float* __restrict__ bias,
               const float* __restrict__ ga, const float* __restrict__ ba,
               const float* __restrict__ gb, const float* __restrict__ bb,
               float* __restrict__ Cf, unsigned short* __restrict__ Cb,
               float* __restrict__ xout,
               int M, int N, const float* __restrict__ Wp2, float* __restrict__ sred)
{
    __shared__ __align__(16) unsigned short As[64 * 264];
    __shared__ __align__(16) unsigned short Bs[64 * 40];
    int tid = threadIdx.x;
    int bm0 = blockIdx.y * 64, bn0 = blockIdx.x * 64;
    int wave = tid >> 6, lane = tid & 63;
    int wm = (wave >> 1) * 32, wn = (wave & 1) * 32;
    int lrow = lane & 15, quad = lane >> 4;
    // ---- prologue: row LayerNorm into As ----
    int prow = tid >> 2, pcb = (tid & 3) * 4;
    const float* pp = pre + (size_t)(bm0 + prow) * HIDN + pcb;
    const float* rp = res + (size_t)(bm0 + prow) * HIDN + pcb;
    float4 v[16];
    float sum = 0.f;
    #pragma unroll
    for (int i = 0; i < 16; i++) {
        float4 a = *(const float4*)(pp + i*16);
        float4 b = *(const float4*)(rp + i*16);
        a.x += b.x; a.y += b.y; a.z += b.z; a.w += b.w;
        v[i] = a;
        sum += a.x + a.y + a.z + a.w;
    }
    sum += __shfl_xor(sum, 1); sum += __shfl_xor(sum, 2);
    float mean = sum * (1.f/256.f);
    float sq = 0.f;
    #pragma unroll
    for (int i = 0; i < 16; i++) {
        float dx = v[i].x-mean, dy = v[i].y-mean, dz = v[i].z-mean, dw = v[i].w-mean;
        sq += dx*dx + dy*dy + dz*dz + dw*dw;
    }
    sq += __shfl_xor(sq, 1); sq += __shfl_xor(sq, 2);
    float rs = rsqrtf(sq * (1.f/256.f) + 1e-5f);
    #pragma unroll
    for (int i = 0; i < 16; i++) {
        float4 g4 = *(const float4*)(ga + pcb + i*16);
        float4 b4 = *(const float4*)(ba + pcb + i*16);
        v[i].x = (v[i].x - mean) * rs * g4.x + b4.x;
        v[i].y = (v[i].y - mean) * rs * g4.y + b4.y;
        v[i].z = (v[i].z - mean) * rs * g4.z + b4.z;
        v[i].w = (v[i].w - mean) * rs * g4.w + b4.w;
    }
    if (DBL) {
        sum = 0.f;
        #pragma unroll
        for (int i = 0; i < 16; i++) sum += v[i].x + v[i].y + v[i].z + v[i].w;
        sum += __shfl_xor(sum, 1); sum += __shfl_xor(sum, 2);
        mean = sum * (1.f/256.f);
        sq = 0.f;
        #pragma unroll
        for (int i = 0; i < 16; i++) {
            float dx = v[i].x-mean, dy = v[i].y-mean, dz = v[i].z-mean, dw = v[i].w-mean;
            sq += dx*dx + dy*dy + dz*dz + dw*dw;
        }
        sq += __shfl_xor(sq, 1); sq += __shfl_xor(sq, 2);
        rs = rsqrtf(sq * (1.f/256.f) + 1e-5f);
        #pragma unroll
        for (int i = 0; i < 16; i++) {
            float4 g4 = *(const float4*)(gb + pcb + i*16);
            float4 b4 = *(const float4*)(bb + pcb + i*16);
            v[i].x = (v[i].x - mean) * rs * g4.x + b4.x;
            v[i].y = (v[i].y - mean) * rs * g4.y + b4.y;
            v[i].z = (v[i].z - mean) * rs * g4.z + b4.z;
            v[i].w = (v[i].w - mean) * rs * g4.w + b4.w;
        }
    }
    #pragma unroll
    for (int i = 0; i < 16; i++) {
        ushort4 us = { f2b(v[i].x), f2b(v[i].y), f2b(v[i].z), f2b(v[i].w) };
        *(ushort4*)(&As[prow*264 + pcb + i*16]) = us;
    }
    if (bn0 == 0) {
        float* xp = xout + (size_t)(bm0 + prow) * HIDN + pcb;
        #pragma unroll
        for (int i = 0; i < 16; i++) *(float4*)(xp + i*16) = v[i];
    }
    // ---- main loop: B streams through Bs, As resident ----
    int srow = tid >> 2, skoff = (tid & 3) * 8;
    const unsigned short* bp = Bt + (size_t)(bn0 + srow) * HIDN + skoff;
    uint4 bv = *(const uint4*)bp;
    f32x4 acc[2][2] = {};
    #pragma unroll
    for (int c = 0; c < 8; ++c) {
        *(uint4*)(&Bs[srow*40 + skoff]) = bv;
        __syncthreads();
        if (c + 1 < 8) bv = *(const uint4*)(bp + (c+1)*32);
        bf16x8 af[2], bfr[2];
        #pragma unroll
        for (int i = 0; i < 2; i++) af[i]  = *(const bf16x8*)(&As[(wm + i*16 + lrow)*264 + c*32 + quad*8]);
        #pragma unroll
        for (int j = 0; j < 2; j++) bfr[j] = *(const bf16x8*)(&Bs[(wn + j*16 + lrow)*40 + quad*8]);
        #pragma unroll
        for (int i = 0; i < 2; i++)
            #pragma unroll
            for (int j = 0; j < 2; j++)
                acc[i][j] = __builtin_amdgcn_mfma_f32_16x16x32_bf16(af[i], bfr[j], acc[i][j], 0, 0, 0);
        __syncthreads();
    }
    if (EPI == 4) {
        #pragma unroll
        for (int i = 0; i < 2; i++) {
            #pragma unroll
            for (int r = 0; r < 4; r++) {
                int row = bm0 + wm + i*16 + quad*4 + r;
                float ps = 0.f;
                #pragma unroll
                for (int j = 0; j < 2; j++) {
                    int col = bn0 + wn + j*16 + lrow;
                    float vv = tanhf(acc[i][j][r] + bias[col]);
                    ps += vv * Wp2[col];
                }
                ps += __shfl_xor(ps, 1);
                ps += __shfl_xor(ps, 2);
                ps += __shfl_xor(ps, 4);
                ps += __shfl_xor(ps, 8);
                if (lrow == 0) atomicAdd(&sred[row], ps);
            }
        }
        return;
    }
    #pragma unroll
    for (int i = 0; i < 2; i++)
        #pragma unroll
        for (int j = 0; j < 2; j++) {
            int col = bn0 + wn + j*16 + lrow;
            float bvv = bias[col];
            #pragma unroll
            for (int r = 0; r < 4; r++) {
                int row = bm0 + wm + i*16 + quad*4 + r;
                float vv = acc[i][j][r] + bvv;
                if (EPI == 1) vv = 0.5f * vv * (1.f + erff(vv * 0.70710678118654752f));
                if (OUT == 0) Cf[(size_t)row*N + col] = vv;
                else          Cb[(size_t)row*N + col] = f2b(vv);
            }
        }
}

// ------------------------------------------------- weight prep (per call) --
__global__ __launch_bounds__(256)
void transpose_all(const float* __restrict__ Wq, const float* __restrict__ Wk,
                   const float* __restrict__ Wv, const float* __restrict__ Wo,
                   const float* __restrict__ Wf1, const float* __restrict__ Wf2,
                   const float* __restrict__ W_node, const float* __restrict__ Wp1,
                   unsigned short* __restrict__ WqkvT, unsigned short* __restrict__ WoT,
                   unsigned short* __restrict__ Wf1T, unsigned short* __restrict__ Wf2T,
                   unsigned short* __restrict__ WnT, unsigned short* __restrict__ Wp1T,
                   const float* __restrict__ nf, unsigned short* __restrict__ nf_b,
                   const float* __restrict__ bq, const float* __restrict__ bk,
                   const float* __restrict__ bv, float* __restrict__ bqkv)
{
    __shared__ unsigned short tile[32][33];
    int bid = blockIdx.x;
    if (bid >= 3168) {   // misc region: nf bf16 convert + qkv bias concat
        int t = (bid - 3168) * 256 + threadIdx.x;
        if (t < NNODE*128) {
            nf_b[t] = f2b(nf[t]);
        } else {
            int u = t - NNODE*128;
            if (u < NLAYER*768) {
                int l = u / 768, j = u % 768;
                float vv = (j < 256) ? bq[l*256 + j] : (j < 512 ? bk[l*256 + j - 256] : bv[l*256 + j - 512]);
                bqkv[u] = vv;
            }
        }
        return;
    }
    const float* s; unsigned short* d; int K, N, n0, k0;
    if (bid < 1024) {
        int mat = bid >> 6, rem = bid & 63;
        int m4 = mat & 3, l = mat >> 2;
        s = (m4 == 0 ? Wq : m4 == 1 ? Wk : m4 == 2 ? Wv : Wo) + (size_t)l * 65536;
        d = (m4 < 3) ? WqkvT + (size_t)l*196608 + (size_t)m4*65536
                     : WoT + (size_t)l*65536;
        K = 256; N = 256; n0 = (rem & 7) * 32; k0 = (rem >> 3) * 32;
    } else if (bid < 2048) {
        int idx = bid - 1024; int l = idx >> 8, rem = idx & 255;
        s = Wf1 + (size_t)l*262144; d = Wf1T + (size_t)l*262144;
        K = 256; N = 1024; n0 = (rem & 31) * 32; k0 = (rem >> 5) * 32;
    } else if (bid < 3072) {
        int idx = bid - 2048; int l = idx >> 8, rem = idx & 255;
        s = Wf2 + (size_t)l*262144; d = Wf2T + (size_t)l*262144;
        K = 1024; N = 256; n0 = (rem & 7) * 32; k0 = (rem >> 3) * 32;
    } else if (bid < 3104) {
        int rem = bid - 3072;
        s = W_node; d = WnT;
        K = 128; N = 256; n0 = (rem & 7) * 32; k0 = (rem >> 3) * 32;
    } else {
        int rem = bid - 3104;
        s = Wp1; d = Wp1T;
        K = 256; N = 256; n0 = (rem & 7) * 32; k0 = (rem >> 3) * 32;
    }
    int tx = threadIdx.x & 31, ty = threadIdx.x >> 5;
    #pragma unroll
    for (int i = 0; i < 4; i++)
        tile[ty + i*8][tx] = f2b(s[(size_t)(k0 + ty + i*8) * N + n0 + tx]);
    __syncthreads();
    #pragma unroll
    for (int i = 0; i < 4; i++)
        d[(size_t)(n0 + ty + i*8) * K + k0 + tx] = tile[tx][ty + i*8];
}

// ------------------------------------------------------- adjacency / CSR ---
__global__ void adj_build(const int* __restrict__ src, const int* __restrict__ dst,
                          unsigned* __restrict__ adjbits)
{
    int t = blockIdx.x * blockDim.x + threadIdx.x;
    if (t < NEDGE) {
        int s = src[t], d = dst[t];
        atomicOr(&adjbits[(size_t)s*64 + (d >> 5)], 1u << (d & 31));
        atomicOr(&adjbits[(size_t)d*64 + (s >> 5)], 1u << (s & 31));
    }
    if (t < NNODE)
        atomicOr(&adjbits[(size_t)t*64 + (t >> 5)], 1u << (t & 31));
}

__global__ void row_rank(const unsigned* __restrict__ adjbits,
                         unsigned* __restrict__ rowcum, int* __restrict__ deg)
{
    int i = blockIdx.x * blockDim.x + threadIdx.x;
    if (i >= NNODE) return;
    unsigned c = 0;
    for (int w = 0; w < 64; w++) {
        rowcum[i*64 + w] = c;
        c += __popc(adjbits[i*64 + w]);
    }
    deg[i] = (int)c;
}

__global__ __launch_bounds__(256)
void scan_kernel(const int* __restrict__ deg, int* __restrict__ rowoff)
{
    __shared__ int part[256];
    int tid = threadIdx.x;
    int base = tid * 8;
    int local[8]; int s = 0;
    #pragma unroll
    for (int k = 0; k < 8; k++) { local[k] = s; s += deg[base + k]; }
    part[tid] = s;
    __syncthreads();
    for (int off = 1; off < 256; off <<= 1) {
        int v = (tid >= off) ? part[tid - off] : 0;
        __syncthreads();
        part[tid] += v;
        __syncthreads();
    }
    int pre = (tid == 0) ? 0 : part[tid - 1];
    #pragma unroll
    for (int k = 0; k < 8; k++) rowoff[base + k] = pre + local[k];
    if (tid == 255) rowoff[NNODE] = part[255];
}

__global__ __launch_bounds__(256)
void fill_cols(const unsigned* __restrict__ adjbits, const int* __restrict__ rowoff,
               const unsigned* __restrict__ rowcum, int* __restrict__ cols)
{
    int t = blockIdx.x * 256 + threadIdx.x;
    int i = t >> 6, w = t & 63;
    unsigned bits = adjbits[(size_t)i*64 + w];
    int base = rowoff[i] + (int)rowcum[(size_t)i*64 + w];
    while (bits) {
        int b = __ffs(bits) - 1;
        cols[base++] = w*32 + b;
        bits &= bits - 1;
    }
}

__global__ void wcomb_kernel(const float* __restrict__ W_edge, const float* __restrict__ b_edge,
                             const float* __restrict__ Wep, const float* __restrict__ bep,
                             float* __restrict__ Wcomb, float* __restrict__ bcomb)
{
    int t = blockIdx.x * blockDim.x + threadIdx.x;
    if (t < 64*32) {
        int k = t >> 5, lh = t & 31, l = lh >> 3, h = lh & 7;
        float acc = 0.f;
        for (int c = 0; c < HIDN; c++)
            acc += W_edge[k*HIDN + c] * Wep[l*HIDN*NHEAD + c*NHEAD + h];
        Wcomb[k*32 + lh] = acc;
    } else if (t < 64*32 + 32) {
        int lh = t - 64*32, l = lh >> 3, h = lh & 7;
        float acc = bep[l*NHEAD + h];
        for (int c = 0; c < HIDN; c++)
            acc += b_edge[c] * Wep[l*HIDN*NHEAD + c*NHEAD + h];
        bcomb[lh] = acc;
    }
}

__global__ __launch_bounds__(256)
void edge_bias_scatter(const float* __restrict__ ef, const float* __restrict__ Wcomb,
                       const float* __restrict__ bcomb,
                       const int* __restrict__ src, const int* __restrict__ dst,
                       const unsigned* __restrict__ adjbits,
                       const unsigned* __restrict__ rowcum,
                       const int* __restrict__ rowoff, float* __restrict__ bias_csr)
{
    __shared__ float Wl[64*32];
    __shared__ float bl[32];
    int tid = threadIdx.x;
    for (int k = tid; k < 64*32; k += 256) Wl[k] = Wcomb[k];
    if (tid < 32) bl[tid] = bcomb[tid];
    __syncthreads();
    int t = blockIdx.x * 256 + tid;
    int e = t >> 5, lh = t & 31;
    const float* f = ef + (size_t)e * 64;
    float acc = bl[lh];
    #pragma unroll
    for (int k = 0; k < 64; k++) acc += f[k] * Wl[k*32 + lh];
    int s = src[e], d = dst[e];
    unsigned wbits = adjbits[(size_t)s*64 + (d >> 5)];
    int rank = (int)rowcum[(size_t)s*64 + (d >> 5)] + __popc(wbits & ((1u << (d & 31)) - 1u));
    int slot = rowoff[s] + rank;
    atomicAdd(&bias_csr[(size_t)slot*32 + lh], acc);
}

// ------------------------------------------------------- sparse attention --
__global__ __launch_bounds__(256)
void attn_kernel(const unsigned short* __restrict__ QKVb, const int* __restrict__ rowoff,
                 const int* __restrict__ cols, const float* __restrict__ bias_csr,
                 unsigned short* __restrict__ ctxb, int layer)
{
    __shared__ float mS[4][8], lS[4][8];
    __shared__ __align__(16) float accS[4][256];
    int i = blockIdx.x;
    int tid = threadIdx.x;
    int w = tid >> 6, lane = tid & 63;
    int h = lane >> 3;
    int off = lane * 4;
    ushort4 qu = *(const ushort4*)(QKVb + (size_t)i*768 + off);
    float4 qf = { b2f(qu.x), b2f(qu.y), b2f(qu.z), b2f(qu.w) };
    int start = rowoff[i], end = rowoff[i+1];
    int lh0 = layer * 8 + h;
    float m = -INFINITY, l = 0.f;
    float4 acc = {0.f, 0.f, 0.f, 0.f};
    for (int c0 = start + w; c0 < end; c0 += 256) {
        int myslot = c0 + 4*lane;
        int mycol = (myslot < end) ? cols[myslot] : 0;
        int lim = min(end, c0 + 256);
        int it = 0;
        for (int slot = c0; slot < lim; slot += 4, ++it) {
            int j = __shfl(mycol, it);
            ushort4 ku = *(const ushort4*)(QKVb + (size_t)j*768 + 256 + off);
            float s = qf.x*b2f(ku.x) + qf.y*b2f(ku.y) + qf.z*b2f(ku.z) + qf.w*b2f(ku.w);
            s += __shfl_xor(s, 1);
            s += __shfl_xor(s, 2);
            s += __shfl_xor(s, 4);
            s = s * 0.17677669529663687f + bias_csr[(size_t)slot*32 + lh0];
            float mn = fmaxf(m, s);
            float sc = __expf(m - mn);
            float p  = __expf(s - mn);
            ushort4 vu = *(const ushort4*)(QKVb + (size_t)j*768 + 512 + off);
            acc.x = acc.x*sc + p*b2f(vu.x);
            acc.y = acc.y*sc + p*b2f(vu.y);
            acc.z = acc.z*sc + p*b2f(vu.z);
            acc.w = acc.w*sc + p*b2f(vu.w);
            l = l*sc + p;
            m = mn;
        }
    }
    if ((lane & 7) == 0) { mS[w][h] = m; lS[w][h] = l; }
    *(float4*)&accS[w][off] = acc;
    __syncthreads();
    if (w == 0) {
        float m0 = mS[0][h], m1 = mS[1][h], m2 = mS[2][h], m3 = mS[3][h];
        float mx = fmaxf(fmaxf(m0, m1), fmaxf(m2, m3));
        float e0 = (m0 == -INFINITY) ? 0.f : __expf(m0 - mx);
        float e1 = (m1 == -INFINITY) ? 0.f : __expf(m1 - mx);
        float e2 = (m2 == -INFINITY) ? 0.f : __expf(m2 - mx);
        float e3 = (m3 == -INFINITY) ? 0.f : __expf(m3 - mx);
        float ls = lS[0][h]*e0 + lS[1][h]*e1 + lS[2][h]*e2 + lS[3][h]*e3;
        float4 a0 = *(float4*)&accS[0][off];
        float4 a1 = *(float4*)&accS[1][off];
        float4 a2 = *(float4*)&accS[2][off];
        float4 a3 = *(float4*)&accS[3][off];
        float inv = 1.f / ls;
        ushort4 o;
        o.x = f2b((a0.x*e0 + a1.x*e1 + a2.x*e2 + a3.x*e3) * inv);
        o.y = f2b((a0.y*e0 + a1.y*e1 + a2.y*e2 + a3.y*e3) * inv);
        o.z = f2b((a0.z*e0 + a1.z*e1 + a2.z*e2 + a3.z*e3) * inv);
        o.w = f2b((a0.w*e0 + a1.w*e1 + a2.w*e2 + a3.w*e3) * inv);
        *(ushort4*)(ctxb + (size_t)i*HIDN + off) = o;
    }
}

// ----------------------------------------- pooling: 16-block partials ------
__global__ __launch_bounds__(256)
void pool_part(const float* __restrict__ x, const float* __restrict__ sred,
               float* __restrict__ partial)
{
    __shared__ float red[4];
    __shared__ float aw[128];
    int b = blockIdx.x, tid = threadIdx.x;
    float mxs = -INFINITY;
    for (int r = tid; r < NNODE; r += 256) mxs = fmaxf(mxs, sred[r]);
    for (int mm = 1; mm < 64; mm <<= 1) mxs = fmaxf(mxs, __shfl_xor(mxs, mm));
    if ((tid & 63) == 0) red[tid >> 6] = mxs;
    __syncthreads();
    mxs = fmaxf(fmaxf(red[0], red[1]), fmaxf(red[2], red[3]));
    __syncthreads();
    float ss = 0.f;
    for (int r = tid; r < NNODE; r += 256) ss += __expf(sred[r] - mxs);
    for (int mm = 1; mm < 64; mm <<= 1) ss += __shfl_xor(ss, mm);
    if ((tid & 63) == 0) red[tid >> 6] = ss;
    __syncthreads();
    ss = red[0] + red[1] + red[2] + red[3];
    float inv = 1.f / ss;
    int r0 = b * 128;
    if (tid < 128) aw[tid] = __expf(sred[r0 + tid] - mxs) * inv;
    __syncthreads();
    float sm = 0.f, mx = -INFINITY, ap = 0.f;
    for (int r = 0; r < 128; r++) {
        float v = x[(size_t)(r0 + r)*HIDN + tid];
        sm += v;
        mx = fmaxf(mx, v);
        ap += v * aw[r];
    }
    partial[(size_t)b*768 + tid]       = sm;
    partial[(size_t)b*768 + 256 + tid] = mx;
    partial[(size_t)b*768 + 512 + tid] = ap;
}

__global__ __launch_bounds__(256)
void pool_fin(const float* __restrict__ partial, float* __restrict__ g)
{
    int c = threadIdx.x;
    float sm = 0.f, mx = -INFINITY, ap = 0.f;
    for (int b = 0; b < 16; b++) {
        sm += partial[(size_t)b*768 + c];
        mx = fmaxf(mx, partial[(size_t)b*768 + 256 + c]);
        ap += partial[(size_t)b*768 + 512 + c];
    }
    g[c]          = sm * (1.f / NNODE);
    g[HIDN + c]   = mx;
    g[2*HIDN + c] = ap;
}

// --------------------------------------------------------------- head ------
__global__ __launch_bounds__(256)
void head1(const float* __restrict__ g, const float* __restrict__ Wo1,
           const float* __restrict__ bo1, float* __restrict__ h1)
{
    __shared__ float hp[4][64];
    int tid = threadIdx.x;
    int w = tid >> 6, lane = tid & 63;
    int j = blockIdx.x * 64 + lane;
    float acc = 0.f;
    int k0 = w * 192;
    for (int k = k0; k < k0 + 192; k++)
        acc += g[k] * Wo1[(size_t)k*512 + j];
    hp[w][lane] = acc;
    __syncthreads();
    if (w == 0) {
        float s = hp[0][lane] + hp[1][lane] + hp[2][lane] + hp[3][lane] + bo1[j];
        h1[j] = fmaxf(s, 0.f);
    }
}

__global__ __launch_bounds__(256)
void head2(const float* __restrict__ h1, const float* __restrict__ Wo2,
           const float* __restrict__ bo2, float* __restrict__ out)
{
    __shared__ float hp[4][64];
    int tid = threadIdx.x;
    int w = tid >> 6, lane = tid & 63;
    int j = blockIdx.x * 64 + lane;
    float acc = 0.f;
    int k0 = w * 128;
    for (int k = k0; k < k0 + 128; k++)
        acc += h1[k] * Wo2[(size_t)k*OUTD + j];
    hp[w][lane] = acc;
    __syncthreads();
    if (w == 0)
        out[j] = hp[0][lane] + hp[1][lane] + hp[2][lane] + hp[3][lane] + bo2[j];
}

// ------------------------------------------------------------- launch ------
extern "C" void kernel_launch(void* const* d_in, const int* in_sizes, int n_in,
                              void* d_out, int out_size, void* d_ws, size_t ws_size,
                              hipStream_t stream)
{
    const float* node_features = (const float*)d_in[0];
    const float* edge_features = (const float*)d_in[1];
    const int*   edge_index    = (const int*)d_in[2];
    const float* W_node = (const float*)d_in[3];
    const float* b_node = (const float*)d_in[4];
    const float* W_edge = (const float*)d_in[5];
    const float* b_edge = (const float*)d_in[6];
    const float* pos_emb = (const float*)d_in[7];
    const float* Wq = (const float*)d_in[8];
    const float* bq = (const float*)d_in[9];
    const float* Wk = (const float*)d_in[10];
    const float* bk = (const float*)d_in[11];
    const float* Wv = (const float*)d_in[12];
    const float* bv = (const float*)d_in[13];
    const float* Wo = (const float*)d_in[14];
    const float* bo = (const float*)d_in[15];
    const float* Wep = (const float*)d_in[16];
    const float* bep = (const float*)d_in[17];
    const float* Wf1 = (const float*)d_in[18];
    const float* bf1 = (const float*)d_in[19];
    const float* Wf2 = (const float*)d_in[20];
    const float* bf2 = (const float*)d_in[21];
    const float* g1  = (const float*)d_in[22];
    const float* be1 = (const float*)d_in[23];
    const float* g2  = (const float*)d_in[24];
    const float* be2 = (const float*)d_in[25];
    const float* g_ln = (const float*)d_in[26];
    const float* b_ln = (const float*)d_in[27];
    const float* Wp1 = (const float*)d_in[28];
    const float* bp1 = (const float*)d_in[29];
    const float* Wp2 = (const float*)d_in[30];
    const float* bp2 = (const float*)d_in[31];
    const float* Wo1 = (const float*)d_in[32];
    const float* bo1 = (const float*)d_in[33];
    const float* Wo2 = (const float*)d_in[34];
    const float* bo2 = (const float*)d_in[35];
    (void)bp2;
    const int* src = edge_index;
    const int* dst = edge_index + NEDGE;

    char* w = (char*)d_ws;
    auto carve = [&](size_t nbytes) {
        void* p = (void*)w;
        w += (nbytes + 255) & ~(size_t)255;
        return p;
    };
    float* xA       = (float*)carve((size_t)NNODE*HIDN*4);
    float* xB       = (float*)carve((size_t)NNODE*HIDN*4);
    unsigned short* xb = (unsigned short*)carve((size_t)NNODE*HIDN*2);
    unsigned short* bufQKVb = (unsigned short*)carve((size_t)NNODE*768*2);
    float* bufO     = (float*)carve((size_t)NNODE*HIDN*4);
    unsigned short* bufAb = (unsigned short*)carve((size_t)NNODE*HIDN*2);
    unsigned short* bufFb = (unsigned short*)carve((size_t)NNODE*FFD*2);
    float* Wcomb    = (float*)carve(64*32*4);
    float* bcomb    = (float*)carve(32*4);
    // adjbits + bias_csr + sbuf contiguous -> single memset
    unsigned* adjbits = (unsigned*)carve((size_t)NNODE*64*4);
    float* bias_csr = (float*)carve((size_t)NNZ_MAX*32*4);
    float* sbuf  = (float*)carve(NNODE*4);
    unsigned* rowcum  = (unsigned*)carve((size_t)NNODE*64*4);
    int* deg    = (int*)carve(NNODE*4);
    int* rowoff = (int*)carve((NNODE+1)*4);
    int* colsb  = (int*)carve((size_t)NNZ_MAX*4);
    float* gbuf  = (float*)carve(3*HIDN*4);
    float* partial = (float*)carve(16*768*4);
    float* h1buf = (float*)carve(512*4);
    unsigned short* nf_b  = (unsigned short*)carve((size_t)NNODE*128*2);
    unsigned short* WnT   = (unsigned short*)carve((size_t)HIDN*128*2);
    unsigned short* WqkvT = (unsigned short*)carve((size_t)NLAYER*768*HIDN*2);
    float*          bqkv  = (float*)carve((size_t)NLAYER*768*4);
    unsigned short* WoT   = (unsigned short*)carve((size_t)NLAYER*HIDN*HIDN*2);
    unsigned short* Wf1T  = (unsigned short*)carve((size_t)NLAYER*FFD*HIDN*2);
    unsigned short* Wf2T  = (unsigned short*)carve((size_t)NLAYER*HIDN*FFD*2);
    unsigned short* Wp1T  = (unsigned short*)carve((size_t)HIDN*HIDN*2);

    // ---- zero adjbits + bias_csr + sbuf in one shot ----
    hipMemsetAsync(adjbits, 0,
                   (size_t)NNODE*64*4 + (size_t)NNZ_MAX*32*4 + (size_t)NNODE*4, stream);
    adj_build<<<(NEDGE+255)/256, 256, 0, stream>>>(src, dst, adjbits);
    row_rank<<<NNODE/256, 256, 0, stream>>>(adjbits, rowcum, deg);
    scan_kernel<<<1, 256, 0, stream>>>(deg, rowoff);
    fill_cols<<<(NNODE*64)/256, 256, 0, stream>>>(adjbits, rowoff, rowcum, colsb);
    wcomb_kernel<<<(64*32+32+255)/256, 256, 0, stream>>>(W_edge, b_edge, Wep, bep, Wcomb, bcomb);
    edge_bias_scatter<<<(NEDGE*32)/256, 256, 0, stream>>>(
        edge_features, Wcomb, bcomb, src, dst, adjbits, rowcum, rowoff, bias_csr);

    // ---- weight prep (transposes + nf convert + bias concat, one launch) ----
    transpose_all<<<3168 + 1024 + 12, 256, 0, stream>>>(
        Wq, Wk, Wv, Wo, Wf1, Wf2, W_node, Wp1,
        WqkvT, WoT, Wf1T, Wf2T, WnT, Wp1T,
        node_features, nf_b, bq, bk, bv, bqkv);

    // ---- node encoding: x0 = nf @ W_node + b_node + pos_emb ----
    mgemm<128,3,2><<<dim3(HIDN/64, NNODE/64), 256, 0, stream>>>(
        nf_b, WnT, b_node, pos_emb, xA, xb, NNODE, HIDN, nullptr, nullptr);

    float* xcur = xA;
    float* xnxt = xB;

    // ---- transformer layers (5 dispatches each) ----
    for (int l = 0; l < NLAYER; l++) {
        if (l == 0) {
            mgemm<256,0,1><<<dim3(768/64, NNODE/64), 256, 0, stream>>>(
                xb, WqkvT, bqkv, nullptr, nullptr, bufQKVb, NNODE, 768, nullptr, nullptr);
        } else {
            // LN2 of previous layer fused: A = LN(x + ff2_out), persists to xnxt
            mgemm_pro<0,1,false><<<dim3(768/64, NNODE/64), 256, 0, stream>>>(
                bufO, xcur, WqkvT + (size_t)l*768*HIDN, bqkv + l*768,
                g2 + (l-1)*HIDN, be2 + (l-1)*HIDN, nullptr, nullptr,
                nullptr, bufQKVb, xnxt, NNODE, 768, nullptr, nullptr);
            { float* t = xcur; xcur = xnxt; xnxt = t; }
        }
        attn_kernel<<<NNODE, 256, 0, stream>>>(bufQKVb, rowoff, colsb, bias_csr, bufAb, l);
        mgemm<256,0,0><<<dim3(HIDN/64, NNODE/64), 256, 0, stream>>>(
            bufAb, WoT + (size_t)l*HIDN*HIDN, bo + l*HIDN, nullptr, bufO, nullptr, NNODE, HIDN, nullptr, nullptr);
        // FF1 with LN1 fused: A = LN(x + attnO), persists to xnxt
        mgemm_pro<1,1,false><<<dim3(FFD/64, NNODE/64), 256, 0, stream>>>(
            bufO, xcur, Wf1T + (size_t)l*FFD*HIDN, bf1 + l*FFD,
            g1 + l*HIDN, be1 + l*HIDN, nullptr, nullptr,
            nullptr, bufFb, xnxt, NNODE, FFD, nullptr, nullptr);
        { float* t = xcur; xcur = xnxt; xnxt = t; }
        mgemm<1024,0,0><<<dim3(HIDN/64, NNODE/64), 256, 0, stream>>>(
            bufFb, Wf2T + (size_t)l*HIDN*FFD, bf2 + l*HIDN, nullptr, bufO, nullptr, NNODE, HIDN, nullptr, nullptr);
    }

    // ---- pooling: Wp1 GEMM with fused LN2(l3)+final LN prologue + score epi ----
    mgemm_pro<4,0,true><<<dim3(HIDN/64, NNODE/64), 256, 0, stream>>>(
        bufO, xcur, Wp1T, bp1,
        g2 + 3*HIDN, be2 + 3*HIDN, g_ln, b_ln,
        nullptr, nullptr, xnxt, NNODE, HIDN, Wp2, sbuf);
    pool_part<<<16, 256, 0, stream>>>(xnxt, sbuf, partial);
    pool_fin<<<1, 256, 0, stream>>>(partial, gbuf);
    head1<<<8, 256, 0, stream>>>(gbuf, Wo1, bo1, h1buf);
    head2<<<OUTD/64, 256, 0, stream>>>(h1buf, Wo2, bo2, (float*)d_out);
}

// Round 9
// 453.326 us; speedup vs baseline: 1.1362x; 1.0670x over previous
//
#include <hip/hip_runtime.h>
#include <math.h>

#define NNODE 2048
#define NEDGE 65536
#define HIDN  256
#define NHEAD 8
#define HDIM  32
#define FFD   1024
#define NLAYER 4
#define OUTD  1280
#define NNZ_MAX (2*NEDGE + NNODE)

typedef __attribute__((ext_vector_type(8))) short bf16x8;
typedef __attribute__((ext_vector_type(4))) float f32x4;

__device__ __forceinline__ unsigned short f2b(float f) {
    unsigned u = __float_as_uint(f);
    unsigned r = (u + 0x7fffu + ((u >> 16) & 1u)) >> 16;
    return (unsigned short)r;
}
__device__ __forceinline__ float b2f(unsigned short u) {
    return __uint_as_float((unsigned)u << 16);
}

// ----------------------------------------------------------- MFMA GEMM -----
// C[M,N] = A[M,K] @ Bt[N,K]^T + bias. 32x64 tile, BK=32, LDS double-buffer +
// register prefetch: ONE barrier per chunk, loads in flight during MFMA.
// Grid = (N/64, M/32): 2-4x blocks/CU vs 64x64 -> latency hidden by TLP.
// EPI: 0=bias, 1=bias+gelu, 3=bias+extra, 4=tanh+pool-reduce(Wp2->sred)
// OUT: 0=fp32 Cf, 1=bf16 Cb, 2=both
template<int K, int EPI, int OUT>
__global__ __launch_bounds__(256)
void mgemm(const unsigned short* __restrict__ A, const unsigned short* __restrict__ Bt,
           const float* __restrict__ bias, const float* __restrict__ extra,
           float* __restrict__ Cf, unsigned short* __restrict__ Cb,
           int M, int N, const float* __restrict__ Wp2, float* __restrict__ sred)
{
    __shared__ __align__(16) unsigned short As[2][32 * 40];
    __shared__ __align__(16) unsigned short Bs[2][64 * 40];
    int tid = threadIdx.x;
    int bm0 = blockIdx.y * 32, bn0 = blockIdx.x * 64;
    int wave = tid >> 6, lane = tid & 63;
    int wm = (wave >> 1) * 16;   // 0 / 16
    int wn = (wave & 1) * 32;    // 0 / 32
    int lrow = lane & 15, quad = lane >> 4;
    int brow = tid >> 2, koff = (tid & 3) * 8;          // B: 64 rows x 4 thr
    int arow = (tid & 127) >> 2;                        // A: tid<128, 32 rows x 4 thr
    bool doA = tid < 128;
    const unsigned short* ap = A  + (size_t)(bm0 + arow) * K + koff;
    const unsigned short* bp = Bt + (size_t)(bn0 + brow) * K + koff;
    uint4 av, bv;
    if (doA) av = *(const uint4*)ap;
    bv = *(const uint4*)bp;
    constexpr int NC = K / 32;
    if (doA) *(uint4*)(&As[0][arow*40 + koff]) = av;
    *(uint4*)(&Bs[0][brow*40 + koff]) = bv;
    __syncthreads();
    f32x4 acc[2] = {};
    #pragma unroll 8
    for (int c = 0; c < NC; ++c) {
        int cur = c & 1;
        if (c + 1 < NC) {
            if (doA) av = *(const uint4*)(ap + (c+1)*32);
            bv = *(const uint4*)(bp + (c+1)*32);
        }
        bf16x8 af = *(const bf16x8*)(&As[cur][(wm + lrow)*40 + quad*8]);
        bf16x8 b0 = *(const bf16x8*)(&Bs[cur][(wn + lrow)*40 + quad*8]);
        bf16x8 b1 = *(const bf16x8*)(&Bs[cur][(wn + 16 + lrow)*40 + quad*8]);
        acc[0] = __builtin_amdgcn_mfma_f32_16x16x32_bf16(af, b0, acc[0], 0, 0, 0);
        acc[1] = __builtin_amdgcn_mfma_f32_16x16x32_bf16(af, b1, acc[1], 0, 0, 0);
        if (c + 1 < NC) {
            if (doA) *(uint4*)(&As[cur^1][arow*40 + koff]) = av;
            *(uint4*)(&Bs[cur^1][brow*40 + koff]) = bv;
        }
        __syncthreads();
    }
    if (EPI == 4) {
        #pragma unroll
        for (int r = 0; r < 4; r++) {
            int row = bm0 + wm + quad*4 + r;
            float ps = 0.f;
            #pragma unroll
            for (int j = 0; j < 2; j++) {
                int col = bn0 + wn + j*16 + lrow;
                float v = tanhf(acc[j][r] + bias[col]);
                ps += v * Wp2[col];
            }
            ps += __shfl_xor(ps, 1);
            ps += __shfl_xor(ps, 2);
            ps += __shfl_xor(ps, 4);
            ps += __shfl_xor(ps, 8);
            if (lrow == 0) atomicAdd(&sred[row], ps);
        }
        return;
    }
    #pragma unroll
    for (int j = 0; j < 2; j++) {
        int col = bn0 + wn + j*16 + lrow;
        float bvv = bias[col];
        #pragma unroll
        for (int r = 0; r < 4; r++) {
            int row = bm0 + wm + quad*4 + r;
            float v = acc[j][r] + bvv;
            if (EPI == 1) v = 0.5f * v * (1.f + erff(v * 0.70710678118654752f));
            else if (EPI == 3) v += extra[(size_t)row*N + col];
            if (OUT == 0 || OUT == 2) Cf[(size_t)row*N + col] = v;
            if (OUT == 1 || OUT == 2) Cb[(size_t)row*N + col] = f2b(v);
        }
    }
}

// ------------------------------------------------- weight prep (per call) --
// All weight transposes + nf convert + bias concat in ONE launch.
__global__ __launch_bounds__(256)
void transpose_all(const float* __restrict__ Wq, const float* __restrict__ Wk,
                   const float* __restrict__ Wv, const float* __restrict__ Wo,
                   const float* __restrict__ Wf1, const float* __restrict__ Wf2,
                   const float* __restrict__ W_node, const float* __restrict__ Wp1,
                   unsigned short* __restrict__ WqkvT, unsigned short* __restrict__ WoT,
                   unsigned short* __restrict__ Wf1T, unsigned short* __restrict__ Wf2T,
                   unsigned short* __restrict__ WnT, unsigned short* __restrict__ Wp1T,
                   const float* __restrict__ nf, unsigned short* __restrict__ nf_b,
                   const float* __restrict__ bq, const float* __restrict__ bk,
                   const float* __restrict__ bv, float* __restrict__ bqkv)
{
    __shared__ unsigned short tile[32][33];
    int bid = blockIdx.x;
    if (bid >= 3168) {   // misc region: nf bf16 convert + qkv bias concat
        int t = (bid - 3168) * 256 + threadIdx.x;
        if (t < NNODE*128) {
            nf_b[t] = f2b(nf[t]);
        } else {
            int u = t - NNODE*128;
            if (u < NLAYER*768) {
                int l = u / 768, j = u % 768;
                float vv = (j < 256) ? bq[l*256 + j] : (j < 512 ? bk[l*256 + j - 256] : bv[l*256 + j - 512]);
                bqkv[u] = vv;
            }
        }
        return;
    }
    const float* s; unsigned short* d; int K, N, n0, k0;
    if (bid < 1024) {
        int mat = bid >> 6, rem = bid & 63;
        int m4 = mat & 3, l = mat >> 2;
        s = (m4 == 0 ? Wq : m4 == 1 ? Wk : m4 == 2 ? Wv : Wo) + (size_t)l * 65536;
        d = (m4 < 3) ? WqkvT + (size_t)l*196608 + (size_t)m4*65536
                     : WoT + (size_t)l*65536;
        K = 256; N = 256; n0 = (rem & 7) * 32; k0 = (rem >> 3) * 32;
    } else if (bid < 2048) {
        int idx = bid - 1024; int l = idx >> 8, rem = idx & 255;
        s = Wf1 + (size_t)l*262144; d = Wf1T + (size_t)l*262144;
        K = 256; N = 1024; n0 = (rem & 31) * 32; k0 = (rem >> 5) * 32;
    } else if (bid < 3072) {
        int idx = bid - 2048; int l = idx >> 8, rem = idx & 255;
        s = Wf2 + (size_t)l*262144; d = Wf2T + (size_t)l*262144;
        K = 1024; N = 256; n0 = (rem & 7) * 32; k0 = (rem >> 3) * 32;
    } else if (bid < 3104) {
        int rem = bid - 3072;
        s = W_node; d = WnT;
        K = 128; N = 256; n0 = (rem & 7) * 32; k0 = (rem >> 3) * 32;
    } else {
        int rem = bid - 3104;
        s = Wp1; d = Wp1T;
        K = 256; N = 256; n0 = (rem & 7) * 32; k0 = (rem >> 3) * 32;
    }
    int tx = threadIdx.x & 31, ty = threadIdx.x >> 5;
    #pragma unroll
    for (int i = 0; i < 4; i++)
        tile[ty + i*8][tx] = f2b(s[(size_t)(k0 + ty + i*8) * N + n0 + tx]);
    __syncthreads();
    #pragma unroll
    for (int i = 0; i < 4; i++)
        d[(size_t)(n0 + ty + i*8) * K + k0 + tx] = tile[tx][ty + i*8];
}

// ------------------------------------------------------- adjacency / CSR ---
__global__ void adj_build(const int* __restrict__ src, const int* __restrict__ dst,
                          unsigned* __restrict__ adjbits)
{
    int t = blockIdx.x * blockDim.x + threadIdx.x;
    if (t < NEDGE) {
        int s = src[t], d = dst[t];
        atomicOr(&adjbits[(size_t)s*64 + (d >> 5)], 1u << (d & 31));
        atomicOr(&adjbits[(size_t)d*64 + (s >> 5)], 1u << (s & 31));
    }
    if (t < NNODE)
        atomicOr(&adjbits[(size_t)t*64 + (t >> 5)], 1u << (t & 31));
}

__global__ void row_rank(const unsigned* __restrict__ adjbits,
                         unsigned* __restrict__ rowcum, int* __restrict__ deg)
{
    int i = blockIdx.x * blockDim.x + threadIdx.x;
    if (i >= NNODE) return;
    unsigned c = 0;
    for (int w = 0; w < 64; w++) {
        rowcum[i*64 + w] = c;
        c += __popc(adjbits[i*64 + w]);
    }
    deg[i] = (int)c;
}

__global__ __launch_bounds__(256)
void scan_kernel(const int* __restrict__ deg, int* __restrict__ rowoff)
{
    __shared__ int part[256];
    int tid = threadIdx.x;
    int base = tid * 8;
    int local[8]; int s = 0;
    #pragma unroll
    for (int k = 0; k < 8; k++) { local[k] = s; s += deg[base + k]; }
    part[tid] = s;
    __syncthreads();
    for (int off = 1; off < 256; off <<= 1) {
        int v = (tid >= off) ? part[tid - off] : 0;
        __syncthreads();
        part[tid] += v;
        __syncthreads();
    }
    int pre = (tid == 0) ? 0 : part[tid - 1];
    #pragma unroll
    for (int k = 0; k < 8; k++) rowoff[base + k] = pre + local[k];
    if (tid == 255) rowoff[NNODE] = part[255];
}

__global__ __launch_bounds__(256)
void fill_cols(const unsigned* __restrict__ adjbits, const int* __restrict__ rowoff,
               const unsigned* __restrict__ rowcum, int* __restrict__ cols)
{
    int t = blockIdx.x * 256 + threadIdx.x;
    int i = t >> 6, w = t & 63;
    unsigned bits = adjbits[(size_t)i*64 + w];
    int base = rowoff[i] + (int)rowcum[(size_t)i*64 + w];
    while (bits) {
        int b = __ffs(bits) - 1;
        cols[base++] = w*32 + b;
        bits &= bits - 1;
    }
}

__global__ void wcomb_kernel(const float* __restrict__ W_edge, const float* __restrict__ b_edge,
                             const float* __restrict__ Wep, const float* __restrict__ bep,
                             float* __restrict__ Wcomb, float* __restrict__ bcomb)
{
    int t = blockIdx.x * blockDim.x + threadIdx.x;
    if (t < 64*32) {
        int k = t >> 5, lh = t & 31, l = lh >> 3, h = lh & 7;
        float acc = 0.f;
        for (int c = 0; c < HIDN; c++)
            acc += W_edge[k*HIDN + c] * Wep[l*HIDN*NHEAD + c*NHEAD + h];
        Wcomb[k*32 + lh] = acc;
    } else if (t < 64*32 + 32) {
        int lh = t - 64*32, l = lh >> 3, h = lh & 7;
        float acc = bep[l*NHEAD + h];
        for (int c = 0; c < HIDN; c++)
            acc += b_edge[c] * Wep[l*HIDN*NHEAD + c*NHEAD + h];
        bcomb[lh] = acc;
    }
}

__global__ __launch_bounds__(256)
void edge_bias_scatter(const float* __restrict__ ef, const float* __restrict__ Wcomb,
                       const float* __restrict__ bcomb,
                       const int* __restrict__ src, const int* __restrict__ dst,
                       const unsigned* __restrict__ adjbits,
                       const unsigned* __restrict__ rowcum,
                       const int* __restrict__ rowoff, float* __restrict__ bias_csr)
{
    __shared__ float Wl[64*32];
    __shared__ float bl[32];
    int tid = threadIdx.x;
    for (int k = tid; k < 64*32; k += 256) Wl[k] = Wcomb[k];
    if (tid < 32) bl[tid] = bcomb[tid];
    __syncthreads();
    int t = blockIdx.x * 256 + tid;
    int e = t >> 5, lh = t & 31;
    const float* f = ef + (size_t)e * 64;
    float acc = bl[lh];
    #pragma unroll
    for (int k = 0; k < 64; k++) acc += f[k] * Wl[k*32 + lh];
    int s = src[e], d = dst[e];
    unsigned wbits = adjbits[(size_t)s*64 + (d >> 5)];
    int rank = (int)rowcum[(size_t)s*64 + (d >> 5)] + __popc(wbits & ((1u << (d & 31)) - 1u));
    int slot = rowoff[s] + rank;
    atomicAdd(&bias_csr[(size_t)slot*32 + lh], acc);
}

// ------------------------------------------------------- sparse attention --
__global__ __launch_bounds__(256)
void attn_kernel(const unsigned short* __restrict__ QKVb, const int* __restrict__ rowoff,
                 const int* __restrict__ cols, const float* __restrict__ bias_csr,
                 unsigned short* __restrict__ ctxb, int layer)
{
    __shared__ float mS[4][8], lS[4][8];
    __shared__ __align__(16) float accS[4][256];
    int i = blockIdx.x;
    int tid = threadIdx.x;
    int w = tid >> 6, lane = tid & 63;
    int h = lane >> 3;
    int off = lane * 4;
    ushort4 qu = *(const ushort4*)(QKVb + (size_t)i*768 + off);
    float4 qf = { b2f(qu.x), b2f(qu.y), b2f(qu.z), b2f(qu.w) };
    int start = rowoff[i], end = rowoff[i+1];
    int lh0 = layer * 8 + h;
    float m = -INFINITY, l = 0.f;
    float4 acc = {0.f, 0.f, 0.f, 0.f};
    for (int c0 = start + w; c0 < end; c0 += 256) {
        int myslot = c0 + 4*lane;
        int mycol = (myslot < end) ? cols[myslot] : 0;
        int lim = min(end, c0 + 256);
        int it = 0;
        for (int slot = c0; slot < lim; slot += 4, ++it) {
            int j = __shfl(mycol, it);
            ushort4 ku = *(const ushort4*)(QKVb + (size_t)j*768 + 256 + off);
            float s = qf.x*b2f(ku.x) + qf.y*b2f(ku.y) + qf.z*b2f(ku.z) + qf.w*b2f(ku.w);
            s += __shfl_xor(s, 1);
            s += __shfl_xor(s, 2);
            s += __shfl_xor(s, 4);
            s = s * 0.17677669529663687f + bias_csr[(size_t)slot*32 + lh0];
            float mn = fmaxf(m, s);
            float sc = __expf(m - mn);
            float p  = __expf(s - mn);
            ushort4 vu = *(const ushort4*)(QKVb + (size_t)j*768 + 512 + off);
            acc.x = acc.x*sc + p*b2f(vu.x);
            acc.y = acc.y*sc + p*b2f(vu.y);
            acc.z = acc.z*sc + p*b2f(vu.z);
            acc.w = acc.w*sc + p*b2f(vu.w);
            l = l*sc + p;
            m = mn;
        }
    }
    if ((lane & 7) == 0) { mS[w][h] = m; lS[w][h] = l; }
    *(float4*)&accS[w][off] = acc;
    __syncthreads();
    if (w == 0) {
        float m0 = mS[0][h], m1 = mS[1][h], m2 = mS[2][h], m3 = mS[3][h];
        float mx = fmaxf(fmaxf(m0, m1), fmaxf(m2, m3));
        float e0 = (m0 == -INFINITY) ? 0.f : __expf(m0 - mx);
        float e1 = (m1 == -INFINITY) ? 0.f : __expf(m1 - mx);
        float e2 = (m2 == -INFINITY) ? 0.f : __expf(m2 - mx);
        float e3 = (m3 == -INFINITY) ? 0.f : __expf(m3 - mx);
        float ls = lS[0][h]*e0 + lS[1][h]*e1 + lS[2][h]*e2 + lS[3][h]*e3;
        float4 a0 = *(float4*)&accS[0][off];
        float4 a1 = *(float4*)&accS[1][off];
        float4 a2 = *(float4*)&accS[2][off];
        float4 a3 = *(float4*)&accS[3][off];
        float inv = 1.f / ls;
        ushort4 o;
        o.x = f2b((a0.x*e0 + a1.x*e1 + a2.x*e2 + a3.x*e3) * inv);
        o.y = f2b((a0.y*e0 + a1.y*e1 + a2.y*e2 + a3.y*e3) * inv);
        o.z = f2b((a0.z*e0 + a1.z*e1 + a2.z*e2 + a3.z*e3) * inv);
        o.w = f2b((a0.w*e0 + a1.w*e1 + a2.w*e2 + a3.w*e3) * inv);
        *(ushort4*)(ctxb + (size_t)i*HIDN + off) = o;
    }
}

// ------------------------------------------------------------ layernorm ----
template<bool RES>
__global__ __launch_bounds__(256)
void ln_kernel(float* __restrict__ x, const float* __restrict__ r,
               const float* __restrict__ g, const float* __restrict__ b,
               unsigned short* __restrict__ xb)
{
    __shared__ float lds[4];
    int row = blockIdx.x, c = threadIdx.x;
    float v = x[(size_t)row*HIDN + c];
    if (RES) v += r[(size_t)row*HIDN + c];
    float s = v;
    for (int mm = 1; mm < 64; mm <<= 1) s += __shfl_xor(s, mm);
    if ((c & 63) == 0) lds[c >> 6] = s;
    __syncthreads();
    float mean = (lds[0] + lds[1] + lds[2] + lds[3]) * (1.f / HIDN);
    __syncthreads();
    float dv = v - mean;
    float qq = dv * dv;
    for (int mm = 1; mm < 64; mm <<= 1) qq += __shfl_xor(qq, mm);
    if ((c & 63) == 0) lds[c >> 6] = qq;
    __syncthreads();
    float var = (lds[0] + lds[1] + lds[2] + lds[3]) * (1.f / HIDN);
    float rs = rsqrtf(var + 1e-5f);
    float o = dv * rs * g[c] + b[c];
    x[(size_t)row*HIDN + c] = o;
    xb[(size_t)row*HIDN + c] = f2b(o);
}

// ----------------------------------------- pooling: 16-block partials ------
__global__ __launch_bounds__(256)
void pool_part(const float* __restrict__ x, const float* __restrict__ sred,
               float* __restrict__ partial)
{
    __shared__ float red[4];
    __shared__ float aw[128];
    int b = blockIdx.x, tid = threadIdx.x;
    float mxs = -INFINITY;
    for (int r = tid; r < NNODE; r += 256) mxs = fmaxf(mxs, sred[r]);
    for (int mm = 1; mm < 64; mm <<= 1) mxs = fmaxf(mxs, __shfl_xor(mxs, mm));
    if ((tid & 63) == 0) red[tid >> 6] = mxs;
    __syncthreads();
    mxs = fmaxf(fmaxf(red[0], red[1]), fmaxf(red[2], red[3]));
    __syncthreads();
    float ss = 0.f;
    for (int r = tid; r < NNODE; r += 256) ss += __expf(sred[r] - mxs);
    for (int mm = 1; mm < 64; mm <<= 1) ss += __shfl_xor(ss, mm);
    if ((tid & 63) == 0) red[tid >> 6] = ss;
    __syncthreads();
    ss = red[0] + red[1] + red[2] + red[3];
    float inv = 1.f / ss;
    int r0 = b * 128;
    if (tid < 128) aw[tid] = __expf(sred[r0 + tid] - mxs) * inv;
    __syncthreads();
    float sm = 0.f, mx = -INFINITY, ap = 0.f;
    for (int r = 0; r < 128; r++) {
        float v = x[(size_t)(r0 + r)*HIDN + tid];
        sm += v;
        mx = fmaxf(mx, v);
        ap += v * aw[r];
    }
    partial[(size_t)b*768 + tid]       = sm;
    partial[(size_t)b*768 + 256 + tid] = mx;
    partial[(size_t)b*768 + 512 + tid] = ap;
}

__global__ __launch_bounds__(256)
void pool_fin(const float* __restrict__ partial, float* __restrict__ g)
{
    int c = threadIdx.x;
    float sm = 0.f, mx = -INFINITY, ap = 0.f;
    for (int b = 0; b < 16; b++) {
        sm += partial[(size_t)b*768 + c];
        mx = fmaxf(mx, partial[(size_t)b*768 + 256 + c]);
        ap += partial[(size_t)b*768 + 512 + c];
    }
    g[c]          = sm * (1.f / NNODE);
    g[HIDN + c]   = mx;
    g[2*HIDN + c] = ap;
}

// --------------------------------------------------------------- head ------
__global__ __launch_bounds__(256)
void head1(const float* __restrict__ g, const float* __restrict__ Wo1,
           const float* __restrict__ bo1, float* __restrict__ h1)
{
    __shared__ float hp[4][64];
    int tid = threadIdx.x;
    int w = tid >> 6, lane = tid & 63;
    int j = blockIdx.x * 64 + lane;
    float acc = 0.f;
    int k0 = w * 192;
    for (int k = k0; k < k0 + 192; k++)
        acc += g[k] * Wo1[(size_t)k*512 + j];
    hp[w][lane] = acc;
    __syncthreads();
    if (w == 0) {
        float s = hp[0][lane] + hp[1][lane] + hp[2][lane] + hp[3][lane] + bo1[j];
        h1[j] = fmaxf(s, 0.f);
    }
}

__global__ __launch_bounds__(256)
void head2(const float* __restrict__ h1, const float* __restrict__ Wo2,
           const float* __restrict__ bo2, float* __restrict__ out)
{
    __shared__ float hp[4][64];
    int tid = threadIdx.x;
    int w = tid >> 6, lane = tid & 63;
    int j = blockIdx.x * 64 + lane;
    float acc = 0.f;
    int k0 = w * 128;
    for (int k = k0; k < k0 + 128; k++)
        acc += h1[k] * Wo2[(size_t)k*OUTD + j];
    hp[w][lane] = acc;
    __syncthreads();
    if (w == 0)
        out[j] = hp[0][lane] + hp[1][lane] + hp[2][lane] + hp[3][lane] + bo2[j];
}

// ------------------------------------------------------------- launch ------
extern "C" void kernel_launch(void* const* d_in, const int* in_sizes, int n_in,
                              void* d_out, int out_size, void* d_ws, size_t ws_size,
                              hipStream_t stream)
{
    const float* node_features = (const float*)d_in[0];
    const float* edge_features = (const float*)d_in[1];
    const int*   edge_index    = (const int*)d_in[2];
    const float* W_node = (const float*)d_in[3];
    const float* b_node = (const float*)d_in[4];
    const float* W_edge = (const float*)d_in[5];
    const float* b_edge = (const float*)d_in[6];
    const float* pos_emb = (const float*)d_in[7];
    const float* Wq = (const float*)d_in[8];
    const float* bq = (const float*)d_in[9];
    const float* Wk = (const float*)d_in[10];
    const float* bk = (const float*)d_in[11];
    const float* Wv = (const float*)d_in[12];
    const float* bv = (const float*)d_in[13];
    const float* Wo = (const float*)d_in[14];
    const float* bo = (const float*)d_in[15];
    const float* Wep = (const float*)d_in[16];
    const float* bep = (const float*)d_in[17];
    const float* Wf1 = (const float*)d_in[18];
    const float* bf1 = (const float*)d_in[19];
    const float* Wf2 = (const float*)d_in[20];
    const float* bf2 = (const float*)d_in[21];
    const float* g1  = (const float*)d_in[22];
    const float* be1 = (const float*)d_in[23];
    const float* g2  = (const float*)d_in[24];
    const float* be2 = (const float*)d_in[25];
    const float* g_ln = (const float*)d_in[26];
    const float* b_ln = (const float*)d_in[27];
    const float* Wp1 = (const float*)d_in[28];
    const float* bp1 = (const float*)d_in[29];
    const float* Wp2 = (const float*)d_in[30];
    const float* bp2 = (const float*)d_in[31];
    const float* Wo1 = (const float*)d_in[32];
    const float* bo1 = (const float*)d_in[33];
    const float* Wo2 = (const float*)d_in[34];
    const float* bo2 = (const float*)d_in[35];
    (void)bp2;
    const int* src = edge_index;
    const int* dst = edge_index + NEDGE;

    char* w = (char*)d_ws;
    auto carve = [&](size_t nbytes) {
        void* p = (void*)w;
        w += (nbytes + 255) & ~(size_t)255;
        return p;
    };
    float* x        = (float*)carve((size_t)NNODE*HIDN*4);
    unsigned short* xb = (unsigned short*)carve((size_t)NNODE*HIDN*2);
    unsigned short* bufQKVb = (unsigned short*)carve((size_t)NNODE*768*2);
    float* bufO     = (float*)carve((size_t)NNODE*HIDN*4);
    unsigned short* bufAb = (unsigned short*)carve((size_t)NNODE*HIDN*2);
    unsigned short* bufFb = (unsigned short*)carve((size_t)NNODE*FFD*2);
    float* Wcomb    = (float*)carve(64*32*4);
    float* bcomb    = (float*)carve(32*4);
    // adjbits + bias_csr + sbuf contiguous -> single memset
    unsigned* adjbits = (unsigned*)carve((size_t)NNODE*64*4);
    float* bias_csr = (float*)carve((size_t)NNZ_MAX*32*4);
    float* sbuf  = (float*)carve(NNODE*4);
    unsigned* rowcum  = (unsigned*)carve((size_t)NNODE*64*4);
    int* deg    = (int*)carve(NNODE*4);
    int* rowoff = (int*)carve((NNODE+1)*4);
    int* colsb  = (int*)carve((size_t)NNZ_MAX*4);
    float* gbuf  = (float*)carve(3*HIDN*4);
    float* partial = (float*)carve(16*768*4);
    float* h1buf = (float*)carve(512*4);
    unsigned short* nf_b  = (unsigned short*)carve((size_t)NNODE*128*2);
    unsigned short* WnT   = (unsigned short*)carve((size_t)HIDN*128*2);
    unsigned short* WqkvT = (unsigned short*)carve((size_t)NLAYER*768*HIDN*2);
    float*          bqkv  = (float*)carve((size_t)NLAYER*768*4);
    unsigned short* WoT   = (unsigned short*)carve((size_t)NLAYER*HIDN*HIDN*2);
    unsigned short* Wf1T  = (unsigned short*)carve((size_t)NLAYER*FFD*HIDN*2);
    unsigned short* Wf2T  = (unsigned short*)carve((size_t)NLAYER*HIDN*FFD*2);
    unsigned short* Wp1T  = (unsigned short*)carve((size_t)HIDN*HIDN*2);

    // ---- zero adjbits + bias_csr + sbuf in one shot ----
    hipMemsetAsync(adjbits, 0,
                   (size_t)NNODE*64*4 + (size_t)NNZ_MAX*32*4 + (size_t)NNODE*4, stream);
    adj_build<<<(NEDGE+255)/256, 256, 0, stream>>>(src, dst, adjbits);
    row_rank<<<NNODE/256, 256, 0, stream>>>(adjbits, rowcum, deg);
    scan_kernel<<<1, 256, 0, stream>>>(deg, rowoff);
    fill_cols<<<(NNODE*64)/256, 256, 0, stream>>>(adjbits, rowoff, rowcum, colsb);
    wcomb_kernel<<<(64*32+32+255)/256, 256, 0, stream>>>(W_edge, b_edge, Wep, bep, Wcomb, bcomb);
    edge_bias_scatter<<<(NEDGE*32)/256, 256, 0, stream>>>(
        edge_features, Wcomb, bcomb, src, dst, adjbits, rowcum, rowoff, bias_csr);

    // ---- weight prep (transposes + nf convert + bias concat, one launch) ----
    transpose_all<<<3168 + 1024 + 12, 256, 0, stream>>>(
        Wq, Wk, Wv, Wo, Wf1, Wf2, W_node, Wp1,
        WqkvT, WoT, Wf1T, Wf2T, WnT, Wp1T,
        node_features, nf_b, bq, bk, bv, bqkv);

    // ---- node encoding: x = nf @ W_node + b_node + pos_emb ----
    mgemm<128,3,2><<<dim3(HIDN/64, NNODE/32), 256, 0, stream>>>(
        nf_b, WnT, b_node, pos_emb, x, xb, NNODE, HIDN, nullptr, nullptr);

    // ---- transformer layers ----
    for (int l = 0; l < NLAYER; l++) {
        mgemm<256,0,1><<<dim3(768/64, NNODE/32), 256, 0, stream>>>(
            xb, WqkvT + (size_t)l*768*HIDN, bqkv + l*768, nullptr, nullptr, bufQKVb, NNODE, 768, nullptr, nullptr);
        attn_kernel<<<NNODE, 256, 0, stream>>>(bufQKVb, rowoff, colsb, bias_csr, bufAb, l);
        mgemm<256,0,0><<<dim3(HIDN/64, NNODE/32), 256, 0, stream>>>(
            bufAb, WoT + (size_t)l*HIDN*HIDN, bo + l*HIDN, nullptr, bufO, nullptr, NNODE, HIDN, nullptr, nullptr);
        ln_kernel<true><<<NNODE, 256, 0, stream>>>(x, bufO, g1 + l*HIDN, be1 + l*HIDN, xb);
        mgemm<256,1,1><<<dim3(FFD/64, NNODE/32), 256, 0, stream>>>(
            xb, Wf1T + (size_t)l*FFD*HIDN, bf1 + l*FFD, nullptr, nullptr, bufFb, NNODE, FFD, nullptr, nullptr);
        mgemm<1024,0,0><<<dim3(HIDN/64, NNODE/32), 256, 0, stream>>>(
            bufFb, Wf2T + (size_t)l*HIDN*FFD, bf2 + l*HIDN, nullptr, bufO, nullptr, NNODE, HIDN, nullptr, nullptr);
        ln_kernel<true><<<NNODE, 256, 0, stream>>>(x, bufO, g2 + l*HIDN, be2 + l*HIDN, xb);
    }

    // ---- final LN + pooling (Wp1 GEMM fused with score reduce) + head ----
    ln_kernel<false><<<NNODE, 256, 0, stream>>>(x, nullptr, g_ln, b_ln, xb);
    mgemm<256,4,0><<<dim3(HIDN/64, NNODE/32), 256, 0, stream>>>(
        xb, Wp1T, bp1, nullptr, nullptr, nullptr, NNODE, HIDN, Wp2, sbuf);
    pool_part<<<16, 256, 0, stream>>>(x, sbuf, partial);
    pool_fin<<<1, 256, 0, stream>>>(partial, gbuf);
    head1<<<8, 256, 0, stream>>>(gbuf, Wo1, bo1, h1buf);
    head2<<<OUTD/64, 256, 0, stream>>>(h1buf, Wo2, bo2, (float*)d_out);
}